// Round 1
// baseline (1091.427 us; speedup 1.0000x reference)
//
#include <hip/hip_runtime.h>
#include <math.h>

#define NN   30000
#define NE   300000
#define ETOT 330000   // NE + NN self loops
#define NB   300
#define EMB  64
#define D1   256      // 4 heads * 64
#define H1   4
#define H3   6
#define O3   121
#define D3   726      // 6 * 121
#define NCLS 10

static inline int ceil_div(int a, int b) { return (a + b - 1) / b; }

// ---------------- setup kernels ----------------

__global__ void zero_kernel(int* __restrict__ cnt, int* __restrict__ gs, int* __restrict__ ge) {
    int i = blockIdx.x * blockDim.x + threadIdx.x;
    if (i < NN) cnt[i] = 0;
    if (i < NB) { gs[i] = 0; ge[i] = 0; }
}

__global__ void h0_kernel(const int* __restrict__ x, const int* __restrict__ dep,
                          const float* __restrict__ nemb, const float* __restrict__ demb,
                          float* __restrict__ h0) {
    int i = blockIdx.x * blockDim.x + threadIdx.x;
    if (i >= NN * EMB) return;
    int n = i >> 6, d = i & 63;
    h0[i] = nemb[x[n] * EMB + d] + demb[dep[n] * EMB + d];
}

__global__ void count_kernel(const int* __restrict__ ei, int* __restrict__ cnt) {
    int e = blockIdx.x * blockDim.x + threadIdx.x;
    if (e >= ETOT) return;
    int dst = (e < NE) ? ei[NE + e] : (e - NE);
    atomicAdd(&cnt[dst], 1);
}

__global__ __launch_bounds__(1024) void scan_kernel(const int* __restrict__ cnt,
                                                    int* __restrict__ rowoff,
                                                    int* __restrict__ fillp) {
    __shared__ int buf[1024];
    __shared__ int carry;
    int tid = threadIdx.x;
    if (tid == 0) carry = 0;
    __syncthreads();
    for (int base = 0; base < NN; base += 1024) {
        int i = base + tid;
        int v = (i < NN) ? cnt[i] : 0;
        buf[tid] = v;
        __syncthreads();
        for (int off = 1; off < 1024; off <<= 1) {
            int t = (tid >= off) ? buf[tid - off] : 0;
            __syncthreads();
            buf[tid] += t;
            __syncthreads();
        }
        int incl = buf[tid];
        int c = carry;
        if (i < NN) {
            int excl = c + incl - v;
            rowoff[i] = excl;
            fillp[i]  = excl;
        }
        __syncthreads();
        if (tid == 0) carry = c + buf[1023];
        __syncthreads();
    }
    if (tid == 0) rowoff[NN] = carry;   // == ETOT
}

__global__ void fill_kernel(const int* __restrict__ ei, int* __restrict__ fillp,
                            int* __restrict__ csr) {
    int e = blockIdx.x * blockDim.x + threadIdx.x;
    if (e >= ETOT) return;
    int src, dst;
    if (e < NE) { src = ei[e]; dst = ei[NE + e]; }
    else        { src = e - NE; dst = e - NE; }
    int slot = atomicAdd(&fillp[dst], 1);
    csr[slot] = src;
}

__global__ void ranges_kernel(const int* __restrict__ batch, int* __restrict__ gs,
                              int* __restrict__ ge) {
    int n = blockIdx.x * blockDim.x + threadIdx.x;
    if (n >= NN) return;
    int b = batch[n];
    if (n == 0 || batch[n - 1] != b) gs[b] = n;
    if (n == NN - 1 || batch[n + 1] != b) ge[b] = n + 1;
}

// ---------------- GEMM (fp32, 64x64 tile, 4x4 per thread) ----------------

__global__ __launch_bounds__(256) void gemm_kernel(const float* __restrict__ Xp,
                                                   const float* __restrict__ Wp,
                                                   float* __restrict__ Pp,
                                                   int M, int K, int Nn) {
    const int BM = 64, BN = 64, BK = 16;
    __shared__ float As[BM][BK + 1];
    __shared__ float Bs[BK][BN + 1];
    int tx = threadIdx.x % 16, ty = threadIdx.x / 16;
    int row0 = blockIdx.y * BM, col0 = blockIdx.x * BN;
    float acc[4][4] = {};
    for (int k0 = 0; k0 < K; k0 += BK) {
        for (int i = threadIdx.x; i < BM * BK; i += 256) {
            int r = i / BK, c = i % BK;
            int gr = row0 + r;
            As[r][c] = (gr < M) ? Xp[(size_t)gr * K + k0 + c] : 0.f;
        }
        for (int i = threadIdx.x; i < BK * BN; i += 256) {
            int r = i / BN, c = i % BN;
            int gc = col0 + c;
            Bs[r][c] = (gc < Nn) ? Wp[(size_t)(k0 + r) * Nn + gc] : 0.f;
        }
        __syncthreads();
        #pragma unroll
        for (int kk = 0; kk < BK; kk++) {
            float a[4], b[4];
            #pragma unroll
            for (int i = 0; i < 4; i++) a[i] = As[ty * 4 + i][kk];
            #pragma unroll
            for (int j = 0; j < 4; j++) b[j] = Bs[kk][tx * 4 + j];
            #pragma unroll
            for (int i = 0; i < 4; i++)
                #pragma unroll
                for (int j = 0; j < 4; j++) acc[i][j] += a[i] * b[j];
        }
        __syncthreads();
    }
    for (int i = 0; i < 4; i++) {
        int gr = row0 + ty * 4 + i;
        if (gr >= M) continue;
        for (int j = 0; j < 4; j++) {
            int gc = col0 + tx * 4 + j;
            if (gc < Nn) Pp[(size_t)gr * Nn + gc] = acc[i][j];
        }
    }
}

// ---------------- attention logits ----------------

template <int H, int D>
__global__ void logits_kernel(const float* __restrict__ P, const float* __restrict__ as_,
                              const float* __restrict__ ad_, float* __restrict__ es,
                              float* __restrict__ ed) {
    int idx = blockIdx.x * blockDim.x + threadIdx.x;
    if (idx >= NN * H) return;
    int node = idx / H, h = idx % H;
    const float* row = P + (size_t)node * (H * D) + h * D;
    float s1 = 0.f, s2 = 0.f;
    #pragma unroll 4
    for (int d = 0; d < D; d++) {
        float v = row[d];
        s1 += v * as_[h * D + d];
        s2 += v * ad_[h * D + d];
    }
    es[idx] = s1;
    ed[idx] = s2;
}

// ---------------- edge softmax (per dst,head) ----------------

template <int H>
__global__ void edge_softmax_kernel(const float* __restrict__ es, const float* __restrict__ ed,
                                    const int* __restrict__ rowoff, const int* __restrict__ csr,
                                    float* __restrict__ exw, float* __restrict__ invs) {
    int idx = blockIdx.x * blockDim.x + threadIdx.x;
    if (idx >= NN * H) return;
    int node = idx / H, h = idx % H;
    int s0 = rowoff[node], s1 = rowoff[node + 1];
    float edv = ed[idx];
    float mx = -3.4e38f;
    for (int s = s0; s < s1; s++) {
        int src = csr[s];
        float v = es[src * H + h] + edv;
        v = v > 0.f ? v : 0.2f * v;
        mx = fmaxf(mx, v);
    }
    float sum = 0.f;
    for (int s = s0; s < s1; s++) {
        int src = csr[s];
        float v = es[src * H + h] + edv;
        v = v > 0.f ? v : 0.2f * v;
        float ex = expf(v - mx);
        exw[s * H + h] = ex;
        sum += ex;
    }
    invs[idx] = 1.f / (sum + 1e-16f);
}

// ---------------- aggregation: one wave per dst node ----------------

template <int H, int D, int CH, bool ELU>
__global__ __launch_bounds__(256) void aggregate_kernel(
    const float* __restrict__ P, const float* __restrict__ exw,
    const float* __restrict__ invs, const int* __restrict__ rowoff,
    const int* __restrict__ csr, const float* __restrict__ bias,
    float* __restrict__ out) {
    const int F = H * D;
    int wave = threadIdx.x >> 6, lane = threadIdx.x & 63;
    int dst = blockIdx.x * (blockDim.x >> 6) + wave;
    if (dst >= NN) return;
    float acc[CH];
    float invv[CH];
    int hh[CH];
    #pragma unroll
    for (int j = 0; j < CH; j++) {
        int f = j * 64 + lane;
        acc[j] = 0.f;
        if (f < F) { hh[j] = f / D; invv[j] = invs[dst * H + hh[j]]; }
        else       { hh[j] = 0;     invv[j] = 0.f; }
    }
    int s0 = rowoff[dst], s1 = rowoff[dst + 1];
    for (int s = s0; s < s1; s++) {
        int src = csr[s];
        const float* prow = P + (size_t)src * F;
        #pragma unroll
        for (int j = 0; j < CH; j++) {
            int f = j * 64 + lane;
            if (f < F) {
                float w = exw[s * H + hh[j]] * invv[j];
                acc[j] += w * prow[f];
            }
        }
    }
    #pragma unroll
    for (int j = 0; j < CH; j++) {
        int f = j * 64 + lane;
        if (f < F) {
            float v = acc[j] + bias[f];
            if (ELU) v = v > 0.f ? v : expm1f(v);
            out[(size_t)dst * F + f] = v;
        }
    }
}

// ---------------- pooling + head-mean + classifier ----------------

__global__ __launch_bounds__(256) void pool_kernel(const float* __restrict__ h3,
                                                   const int* __restrict__ gs,
                                                   const int* __restrict__ ge,
                                                   const float* __restrict__ wp,
                                                   const float* __restrict__ bp,
                                                   float* __restrict__ out) {
    __shared__ float g[O3];
    int b = blockIdx.x;
    int tid = threadIdx.x;
    if (tid < O3) g[tid] = 0.f;
    __syncthreads();
    int s = gs[b], e = ge[b];
    for (int f = tid; f < D3; f += 256) {
        float sum = 0.f;
        for (int n = s; n < e; n++) sum += h3[(size_t)n * D3 + f];
        int k = f;
        while (k >= O3) k -= O3;
        atomicAdd(&g[k], sum);
    }
    __syncthreads();
    int cntn = e - s;
    float scale = 1.f / (6.f * (float)(cntn > 0 ? cntn : 1));
    if (tid < NCLS) {
        float o = bp[tid];
        for (int k = 0; k < O3; k++) o += g[k] * scale * wp[k * NCLS + tid];
        out[b * NCLS + tid] = o;
    }
}

// ---------------- launch ----------------

extern "C" void kernel_launch(void* const* d_in, const int* in_sizes, int n_in,
                              void* d_out, int out_size, void* d_ws, size_t ws_size,
                              hipStream_t stream) {
    const int* x     = (const int*)d_in[0];
    const int* dep   = (const int*)d_in[1];
    const int* ei    = (const int*)d_in[2];
    const int* batch = (const int*)d_in[3];
    const float* nemb = (const float*)d_in[4];
    const float* demb = (const float*)d_in[5];
    const float* w1  = (const float*)d_in[6];
    const float* as1 = (const float*)d_in[7];
    const float* ad1 = (const float*)d_in[8];
    const float* b1  = (const float*)d_in[9];
    const float* w2  = (const float*)d_in[10];
    const float* as2 = (const float*)d_in[11];
    const float* ad2 = (const float*)d_in[12];
    const float* b2  = (const float*)d_in[13];
    const float* w3  = (const float*)d_in[14];
    const float* as3 = (const float*)d_in[15];
    const float* ad3 = (const float*)d_in[16];
    const float* b3  = (const float*)d_in[17];
    const float* wp  = (const float*)d_in[18];
    const float* bp  = (const float*)d_in[19];
    float* out = (float*)d_out;

    char* ws = (char*)d_ws;
    size_t off = 0;
    auto alloc = [&](size_t bytes) -> void* {
        void* p = ws + off;
        off += (bytes + 255) & ~(size_t)255;
        return p;
    };
    float* A    = (float*)alloc((size_t)NN * D1 * 4);   // conv1 in (stride 64) / conv2 out / conv3 in
    float* Pb   = (float*)alloc((size_t)NN * D3 * 4);   // projected features per conv
    float* Ob   = (float*)alloc((size_t)NN * D3 * 4);   // conv1 out / conv2 in / conv3 out
    float* es   = (float*)alloc((size_t)NN * 6 * 4);
    float* ed   = (float*)alloc((size_t)NN * 6 * 4);
    float* invs = (float*)alloc((size_t)NN * 6 * 4);
    float* exw  = (float*)alloc((size_t)ETOT * 6 * 4);
    int* cnt    = (int*)alloc((size_t)NN * 4);
    int* rowoff = (int*)alloc((size_t)(NN + 1) * 4);
    int* fillp  = (int*)alloc((size_t)NN * 4);
    int* csr    = (int*)alloc((size_t)ETOT * 4);
    int* gs     = (int*)alloc((size_t)NB * 4);
    int* ge     = (int*)alloc((size_t)NB * 4);

    // --- graph preprocessing ---
    zero_kernel<<<ceil_div(NN, 256), 256, 0, stream>>>(cnt, gs, ge);
    h0_kernel<<<ceil_div(NN * EMB, 256), 256, 0, stream>>>(x, dep, nemb, demb, A);
    count_kernel<<<ceil_div(ETOT, 256), 256, 0, stream>>>(ei, cnt);
    scan_kernel<<<1, 1024, 0, stream>>>(cnt, rowoff, fillp);
    fill_kernel<<<ceil_div(ETOT, 256), 256, 0, stream>>>(ei, fillp, csr);
    ranges_kernel<<<ceil_div(NN, 256), 256, 0, stream>>>(batch, gs, ge);

    // --- conv1: [NN,64] -> [NN,256], 4 heads x 64 ---
    gemm_kernel<<<dim3(ceil_div(D1, 64), ceil_div(NN, 64)), 256, 0, stream>>>(A, w1, Pb, NN, EMB, D1);
    logits_kernel<H1, EMB><<<ceil_div(NN * H1, 256), 256, 0, stream>>>(Pb, as1, ad1, es, ed);
    edge_softmax_kernel<H1><<<ceil_div(NN * H1, 256), 256, 0, stream>>>(es, ed, rowoff, csr, exw, invs);
    aggregate_kernel<H1, EMB, 4, true><<<ceil_div(NN, 4), 256, 0, stream>>>(Pb, exw, invs, rowoff, csr, b1, Ob);

    // --- conv2: [NN,256] -> [NN,256] ---
    gemm_kernel<<<dim3(ceil_div(D1, 64), ceil_div(NN, 64)), 256, 0, stream>>>(Ob, w2, Pb, NN, D1, D1);
    logits_kernel<H1, EMB><<<ceil_div(NN * H1, 256), 256, 0, stream>>>(Pb, as2, ad2, es, ed);
    edge_softmax_kernel<H1><<<ceil_div(NN * H1, 256), 256, 0, stream>>>(es, ed, rowoff, csr, exw, invs);
    aggregate_kernel<H1, EMB, 4, true><<<ceil_div(NN, 4), 256, 0, stream>>>(Pb, exw, invs, rowoff, csr, b2, A);

    // --- conv3: [NN,256] -> [NN,726], 6 heads x 121, no ELU ---
    gemm_kernel<<<dim3(ceil_div(D3, 64), ceil_div(NN, 64)), 256, 0, stream>>>(A, w3, Pb, NN, D1, D3);
    logits_kernel<H3, O3><<<ceil_div(NN * H3, 256), 256, 0, stream>>>(Pb, as3, ad3, es, ed);
    edge_softmax_kernel<H3><<<ceil_div(NN * H3, 256), 256, 0, stream>>>(es, ed, rowoff, csr, exw, invs);
    aggregate_kernel<H3, O3, 12, false><<<ceil_div(NN, 4), 256, 0, stream>>>(Pb, exw, invs, rowoff, csr, b3, Ob);

    // --- pool + classify ---
    pool_kernel<<<NB, 256, 0, stream>>>(Ob, gs, ge, wp, bp, out);
}

// Round 2
// 790.676 us; speedup vs baseline: 1.3804x; 1.3804x over previous
//
#include <hip/hip_runtime.h>
#include <hip/hip_bf16.h>
#include <math.h>

#define NN   30000
#define NE   300000
#define ETOT 330000   // NE + NN self loops
#define NB   300
#define EMB  64
#define D1   256      // 4 heads * 64
#define H1   4
#define H3   6
#define O3   121
#define D3   726      // 6 * 121
#define NCLS 10

typedef __attribute__((ext_vector_type(8))) short short8;
typedef __attribute__((ext_vector_type(4))) float floatx4;

static inline int ceil_div(int a, int b) { return (a + b - 1) / b; }

__device__ inline void split_bf16(float f, unsigned short& hi, unsigned short& lo) {
    __hip_bfloat16 h = __float2bfloat16(f);
    float fh = __bfloat162float(h);
    __hip_bfloat16 l = __float2bfloat16(f - fh);
    hi = __builtin_bit_cast(unsigned short, h);
    lo = __builtin_bit_cast(unsigned short, l);
}

// ---------------- setup kernels ----------------

__global__ void zero_kernel(int* __restrict__ cnt, int* __restrict__ gs, int* __restrict__ ge) {
    int i = blockIdx.x * blockDim.x + threadIdx.x;
    if (i < NN) cnt[i] = 0;
    if (i < NB) { gs[i] = 0; ge[i] = 0; }
}

// node encoder -> split bf16 directly (feeds gemm1 only)
__global__ void h0_kernel(const int* __restrict__ x, const int* __restrict__ dep,
                          const float* __restrict__ nemb, const float* __restrict__ demb,
                          unsigned short* __restrict__ hi, unsigned short* __restrict__ lo) {
    int i = blockIdx.x * blockDim.x + threadIdx.x;
    if (i >= NN * EMB) return;
    int n = i >> 6, d = i & 63;
    float v = nemb[x[n] * EMB + d] + demb[dep[n] * EMB + d];
    split_bf16(v, hi[i], lo[i]);
}

// weight [K x N] fp32 -> transposed split bf16 [N x K]
__global__ void convB_kernel(const float* __restrict__ W, unsigned short* __restrict__ bthi,
                             unsigned short* __restrict__ btlo, int K, int N) {
    int idx = blockIdx.x * blockDim.x + threadIdx.x;
    if (idx >= K * N) return;
    int k = idx / N, n = idx % N;
    unsigned short h, l;
    split_bf16(W[idx], h, l);
    bthi[n * K + k] = h;
    btlo[n * K + k] = l;
}

__global__ void count_kernel(const int* __restrict__ ei, int* __restrict__ cnt) {
    int e = blockIdx.x * blockDim.x + threadIdx.x;
    if (e >= ETOT) return;
    int dst = (e < NE) ? ei[NE + e] : (e - NE);
    atomicAdd(&cnt[dst], 1);
}

__global__ __launch_bounds__(1024) void scan_kernel(const int* __restrict__ cnt,
                                                    int* __restrict__ rowoff,
                                                    int* __restrict__ fillp) {
    __shared__ int buf[1024];
    __shared__ int carry;
    int tid = threadIdx.x;
    if (tid == 0) carry = 0;
    __syncthreads();
    for (int base = 0; base < NN; base += 1024) {
        int i = base + tid;
        int v = (i < NN) ? cnt[i] : 0;
        buf[tid] = v;
        __syncthreads();
        for (int off = 1; off < 1024; off <<= 1) {
            int t = (tid >= off) ? buf[tid - off] : 0;
            __syncthreads();
            buf[tid] += t;
            __syncthreads();
        }
        int incl = buf[tid];
        int c = carry;
        if (i < NN) {
            int excl = c + incl - v;
            rowoff[i] = excl;
            fillp[i]  = excl;
        }
        __syncthreads();
        if (tid == 0) carry = c + buf[1023];
        __syncthreads();
    }
    if (tid == 0) rowoff[NN] = carry;   // == ETOT
}

__global__ void fill_kernel(const int* __restrict__ ei, int* __restrict__ fillp,
                            int* __restrict__ csr) {
    int e = blockIdx.x * blockDim.x + threadIdx.x;
    if (e >= ETOT) return;
    int src, dst;
    if (e < NE) { src = ei[e]; dst = ei[NE + e]; }
    else        { src = e - NE; dst = e - NE; }
    int slot = atomicAdd(&fillp[dst], 1);
    csr[slot] = src;
}

__global__ void ranges_kernel(const int* __restrict__ batch, int* __restrict__ gs,
                              int* __restrict__ ge) {
    int n = blockIdx.x * blockDim.x + threadIdx.x;
    if (n >= NN) return;
    int b = batch[n];
    if (n == 0 || batch[n - 1] != b) gs[b] = n;
    if (n == NN - 1 || batch[n + 1] != b) ge[b] = n + 1;
}

// ---------------- MFMA GEMM: C[MxN] = A[MxK] * BT[NxK]^T, split-bf16 ----------------
// 128x128 block tile, 4 waves (2x2), each wave 64x64 via 4x4 mfma_f32_16x16x32_bf16.
// LDS rows padded to 40 elems (80B): conflict-spread AND 16B aligned.

#define LDA 40

__global__ __launch_bounds__(256) void gemm_mfma_kernel(
    const unsigned short* __restrict__ Ahi, const unsigned short* __restrict__ Alo,
    const unsigned short* __restrict__ Bhi, const unsigned short* __restrict__ Blo,
    float* __restrict__ C, int M, int K, int N) {
    __shared__ unsigned short sAh[128 * LDA], sAl[128 * LDA];
    __shared__ unsigned short sBh[128 * LDA], sBl[128 * LDA];
    int tid = threadIdx.x;
    int lane = tid & 63, wave = tid >> 6;
    int wr = (wave >> 1) * 64, wc = (wave & 1) * 64;
    int quad = lane >> 4, mr = lane & 15;
    int row0 = blockIdx.y * 128, col0 = blockIdx.x * 128;

    floatx4 zero = {0.f, 0.f, 0.f, 0.f};
    floatx4 acc[4][4];
    #pragma unroll
    for (int i = 0; i < 4; i++)
        #pragma unroll
        for (int j = 0; j < 4; j++) acc[i][j] = zero;

    for (int k0 = 0; k0 < K; k0 += 32) {
        #pragma unroll
        for (int ch = 0; ch < 2; ch++) {
            int linear = (ch * 256 + tid) * 8;   // 128*32 = 4096 elements
            int r = linear >> 5, c = linear & 31;
            uint4 vh, vl;
            int gr = row0 + r;
            if (gr < M) {
                vh = *(const uint4*)(Ahi + (size_t)gr * K + k0 + c);
                vl = *(const uint4*)(Alo + (size_t)gr * K + k0 + c);
            } else { vh = uint4{0, 0, 0, 0}; vl = uint4{0, 0, 0, 0}; }
            *(uint4*)&sAh[r * LDA + c] = vh;
            *(uint4*)&sAl[r * LDA + c] = vl;
            int gn = col0 + r;
            if (gn < N) {
                vh = *(const uint4*)(Bhi + (size_t)gn * K + k0 + c);
                vl = *(const uint4*)(Blo + (size_t)gn * K + k0 + c);
            } else { vh = uint4{0, 0, 0, 0}; vl = uint4{0, 0, 0, 0}; }
            *(uint4*)&sBh[r * LDA + c] = vh;
            *(uint4*)&sBl[r * LDA + c] = vl;
        }
        __syncthreads();

        short8 ah[4], al[4], bh[4], bl[4];
        #pragma unroll
        for (int i = 0; i < 4; i++) {
            int ar = wr + i * 16 + mr;
            ah[i] = *(const short8*)&sAh[ar * LDA + quad * 8];
            al[i] = *(const short8*)&sAl[ar * LDA + quad * 8];
            int br = wc + i * 16 + mr;
            bh[i] = *(const short8*)&sBh[br * LDA + quad * 8];
            bl[i] = *(const short8*)&sBl[br * LDA + quad * 8];
        }
        #pragma unroll
        for (int i = 0; i < 4; i++)
            #pragma unroll
            for (int j = 0; j < 4; j++) {
                acc[i][j] = __builtin_amdgcn_mfma_f32_16x16x32_bf16(ah[i], bh[j], acc[i][j], 0, 0, 0);
                acc[i][j] = __builtin_amdgcn_mfma_f32_16x16x32_bf16(ah[i], bl[j], acc[i][j], 0, 0, 0);
                acc[i][j] = __builtin_amdgcn_mfma_f32_16x16x32_bf16(al[i], bh[j], acc[i][j], 0, 0, 0);
            }
        __syncthreads();
    }

    #pragma unroll
    for (int i = 0; i < 4; i++) {
        #pragma unroll
        for (int j = 0; j < 4; j++) {
            int gc = col0 + wc + j * 16 + mr;
            if (gc >= N) continue;
            int gr0 = row0 + wr + i * 16 + quad * 4;
            #pragma unroll
            for (int r = 0; r < 4; r++) {
                int gr = gr0 + r;
                if (gr < M) C[(size_t)gr * N + gc] = acc[i][j][r];
            }
        }
    }
}

// ---------------- attention logits ----------------

template <int H, int D>
__global__ void logits_kernel(const float* __restrict__ P, const float* __restrict__ as_,
                              const float* __restrict__ ad_, float* __restrict__ es,
                              float* __restrict__ ed) {
    int idx = blockIdx.x * blockDim.x + threadIdx.x;
    if (idx >= NN * H) return;
    int node = idx / H, h = idx % H;
    const float* row = P + (size_t)node * (H * D) + h * D;
    float s1 = 0.f, s2 = 0.f;
    #pragma unroll 4
    for (int d = 0; d < D; d++) {
        float v = row[d];
        s1 += v * as_[h * D + d];
        s2 += v * ad_[h * D + d];
    }
    es[idx] = s1;
    ed[idx] = s2;
}

// ---------------- edge softmax (per dst,head) ----------------

template <int H>
__global__ void edge_softmax_kernel(const float* __restrict__ es, const float* __restrict__ ed,
                                    const int* __restrict__ rowoff, const int* __restrict__ csr,
                                    float* __restrict__ exw, float* __restrict__ invs) {
    int idx = blockIdx.x * blockDim.x + threadIdx.x;
    if (idx >= NN * H) return;
    int node = idx / H, h = idx % H;
    int s0 = rowoff[node], s1 = rowoff[node + 1];
    float edv = ed[idx];
    float mx = -3.4e38f;
    for (int s = s0; s < s1; s++) {
        int src = csr[s];
        float v = es[src * H + h] + edv;
        v = v > 0.f ? v : 0.2f * v;
        mx = fmaxf(mx, v);
    }
    float sum = 0.f;
    for (int s = s0; s < s1; s++) {
        int src = csr[s];
        float v = es[src * H + h] + edv;
        v = v > 0.f ? v : 0.2f * v;
        float ex = expf(v - mx);
        exw[s * H + h] = ex;
        sum += ex;
    }
    invs[idx] = 1.f / (sum + 1e-16f);
}

// ---------------- aggregation: one wave per dst node ----------------

template <int H, int D, int CH, bool ELU, bool BF16OUT>
__global__ __launch_bounds__(256) void aggregate_kernel(
    const float* __restrict__ P, const float* __restrict__ exw,
    const float* __restrict__ invs, const int* __restrict__ rowoff,
    const int* __restrict__ csr, const float* __restrict__ bias,
    float* __restrict__ outF, unsigned short* __restrict__ outHi,
    unsigned short* __restrict__ outLo) {
    const int F = H * D;
    int wave = threadIdx.x >> 6, lane = threadIdx.x & 63;
    int dst = blockIdx.x * (blockDim.x >> 6) + wave;
    if (dst >= NN) return;
    float acc[CH];
    float invv[CH];
    int hh[CH];
    #pragma unroll
    for (int j = 0; j < CH; j++) {
        int f = j * 64 + lane;
        acc[j] = 0.f;
        if (f < F) { hh[j] = f / D; invv[j] = invs[dst * H + hh[j]]; }
        else       { hh[j] = 0;     invv[j] = 0.f; }
    }
    int s0 = rowoff[dst], s1 = rowoff[dst + 1];
    for (int s = s0; s < s1; s++) {
        int src = csr[s];
        const float* prow = P + (size_t)src * F;
        #pragma unroll
        for (int j = 0; j < CH; j++) {
            int f = j * 64 + lane;
            if (f < F) {
                float w = exw[s * H + hh[j]] * invv[j];
                acc[j] += w * prow[f];
            }
        }
    }
    #pragma unroll
    for (int j = 0; j < CH; j++) {
        int f = j * 64 + lane;
        if (f < F) {
            float v = acc[j] + bias[f];
            if (ELU) v = v > 0.f ? v : expm1f(v);
            size_t idx = (size_t)dst * F + f;
            if (BF16OUT) {
                unsigned short h, l;
                split_bf16(v, h, l);
                outHi[idx] = h;
                outLo[idx] = l;
            } else {
                outF[idx] = v;
            }
        }
    }
}

// ---------------- pooling + head-mean + classifier ----------------

__global__ __launch_bounds__(256) void pool_kernel(const float* __restrict__ h3,
                                                   const int* __restrict__ gs,
                                                   const int* __restrict__ ge,
                                                   const float* __restrict__ wp,
                                                   const float* __restrict__ bp,
                                                   float* __restrict__ out) {
    __shared__ float g[O3];
    int b = blockIdx.x;
    int tid = threadIdx.x;
    if (tid < O3) g[tid] = 0.f;
    __syncthreads();
    int s = gs[b], e = ge[b];
    for (int f = tid; f < D3; f += 256) {
        float sum = 0.f;
        for (int n = s; n < e; n++) sum += h3[(size_t)n * D3 + f];
        int k = f;
        while (k >= O3) k -= O3;
        atomicAdd(&g[k], sum);
    }
    __syncthreads();
    int cntn = e - s;
    float scale = 1.f / (6.f * (float)(cntn > 0 ? cntn : 1));
    if (tid < NCLS) {
        float o = bp[tid];
        for (int k = 0; k < O3; k++) o += g[k] * scale * wp[k * NCLS + tid];
        out[b * NCLS + tid] = o;
    }
}

// ---------------- launch ----------------

extern "C" void kernel_launch(void* const* d_in, const int* in_sizes, int n_in,
                              void* d_out, int out_size, void* d_ws, size_t ws_size,
                              hipStream_t stream) {
    const int* x     = (const int*)d_in[0];
    const int* dep   = (const int*)d_in[1];
    const int* ei    = (const int*)d_in[2];
    const int* batch = (const int*)d_in[3];
    const float* nemb = (const float*)d_in[4];
    const float* demb = (const float*)d_in[5];
    const float* w1  = (const float*)d_in[6];
    const float* as1 = (const float*)d_in[7];
    const float* ad1 = (const float*)d_in[8];
    const float* b1  = (const float*)d_in[9];
    const float* w2  = (const float*)d_in[10];
    const float* as2 = (const float*)d_in[11];
    const float* ad2 = (const float*)d_in[12];
    const float* b2  = (const float*)d_in[13];
    const float* w3  = (const float*)d_in[14];
    const float* as3 = (const float*)d_in[15];
    const float* ad3 = (const float*)d_in[16];
    const float* b3  = (const float*)d_in[17];
    const float* wp  = (const float*)d_in[18];
    const float* bp  = (const float*)d_in[19];
    float* out = (float*)d_out;

    char* ws = (char*)d_ws;
    size_t off = 0;
    auto alloc = [&](size_t bytes) -> void* {
        void* p = ws + off;
        off += (bytes + 255) & ~(size_t)255;
        return p;
    };
    unsigned short* Hhi = (unsigned short*)alloc((size_t)NN * D1 * 2);  // gemm input hi (layer-reused)
    unsigned short* Hlo = (unsigned short*)alloc((size_t)NN * D1 * 2);  // gemm input lo
    unsigned short* Whi = (unsigned short*)alloc((size_t)D3 * D1 * 2);  // weight^T hi
    unsigned short* Wlo = (unsigned short*)alloc((size_t)D3 * D1 * 2);  // weight^T lo
    float* Pb   = (float*)alloc((size_t)NN * D3 * 4);   // projected features per conv
    float* Ob   = (float*)alloc((size_t)NN * D3 * 4);   // conv3 out (fp32) for pooling
    float* es   = (float*)alloc((size_t)NN * 6 * 4);
    float* ed   = (float*)alloc((size_t)NN * 6 * 4);
    float* invs = (float*)alloc((size_t)NN * 6 * 4);
    float* exw  = (float*)alloc((size_t)ETOT * 6 * 4);
    int* cnt    = (int*)alloc((size_t)NN * 4);
    int* rowoff = (int*)alloc((size_t)(NN + 1) * 4);
    int* fillp  = (int*)alloc((size_t)NN * 4);
    int* csr    = (int*)alloc((size_t)ETOT * 4);
    int* gs     = (int*)alloc((size_t)NB * 4);
    int* ge     = (int*)alloc((size_t)NB * 4);

    // --- graph preprocessing ---
    zero_kernel<<<ceil_div(NN, 256), 256, 0, stream>>>(cnt, gs, ge);
    h0_kernel<<<ceil_div(NN * EMB, 256), 256, 0, stream>>>(x, dep, nemb, demb, Hhi, Hlo);
    count_kernel<<<ceil_div(ETOT, 256), 256, 0, stream>>>(ei, cnt);
    scan_kernel<<<1, 1024, 0, stream>>>(cnt, rowoff, fillp);
    fill_kernel<<<ceil_div(ETOT, 256), 256, 0, stream>>>(ei, fillp, csr);
    ranges_kernel<<<ceil_div(NN, 256), 256, 0, stream>>>(batch, gs, ge);

    // --- conv1: [NN,64] -> [NN,256], 4 heads x 64 ---
    convB_kernel<<<ceil_div(EMB * D1, 256), 256, 0, stream>>>(w1, Whi, Wlo, EMB, D1);
    gemm_mfma_kernel<<<dim3(ceil_div(D1, 128), ceil_div(NN, 128)), 256, 0, stream>>>(
        Hhi, Hlo, Whi, Wlo, Pb, NN, EMB, D1);
    logits_kernel<H1, EMB><<<ceil_div(NN * H1, 256), 256, 0, stream>>>(Pb, as1, ad1, es, ed);
    edge_softmax_kernel<H1><<<ceil_div(NN * H1, 256), 256, 0, stream>>>(es, ed, rowoff, csr, exw, invs);
    aggregate_kernel<H1, EMB, 4, true, true><<<ceil_div(NN, 4), 256, 0, stream>>>(
        Pb, exw, invs, rowoff, csr, b1, nullptr, Hhi, Hlo);

    // --- conv2: [NN,256] -> [NN,256] ---
    convB_kernel<<<ceil_div(D1 * D1, 256), 256, 0, stream>>>(w2, Whi, Wlo, D1, D1);
    gemm_mfma_kernel<<<dim3(ceil_div(D1, 128), ceil_div(NN, 128)), 256, 0, stream>>>(
        Hhi, Hlo, Whi, Wlo, Pb, NN, D1, D1);
    logits_kernel<H1, EMB><<<ceil_div(NN * H1, 256), 256, 0, stream>>>(Pb, as2, ad2, es, ed);
    edge_softmax_kernel<H1><<<ceil_div(NN * H1, 256), 256, 0, stream>>>(es, ed, rowoff, csr, exw, invs);
    aggregate_kernel<H1, EMB, 4, true, true><<<ceil_div(NN, 4), 256, 0, stream>>>(
        Pb, exw, invs, rowoff, csr, b2, nullptr, Hhi, Hlo);

    // --- conv3: [NN,256] -> [NN,726], 6 heads x 121, no ELU ---
    convB_kernel<<<ceil_div(D1 * D3, 256), 256, 0, stream>>>(w3, Whi, Wlo, D1, D3);
    gemm_mfma_kernel<<<dim3(ceil_div(D3, 128), ceil_div(NN, 128)), 256, 0, stream>>>(
        Hhi, Hlo, Whi, Wlo, Pb, NN, D1, D3);
    logits_kernel<H3, O3><<<ceil_div(NN * H3, 256), 256, 0, stream>>>(Pb, as3, ad3, es, ed);
    edge_softmax_kernel<H3><<<ceil_div(NN * H3, 256), 256, 0, stream>>>(es, ed, rowoff, csr, exw, invs);
    aggregate_kernel<H3, O3, 12, false, false><<<ceil_div(NN, 4), 256, 0, stream>>>(
        Pb, exw, invs, rowoff, csr, b3, Ob, nullptr, nullptr);

    // --- pool + classify ---
    pool_kernel<<<NB, 256, 0, stream>>>(Ob, gs, ge, wp, bp, out);
}

// Round 3
// 600.817 us; speedup vs baseline: 1.8166x; 1.3160x over previous
//
#include <hip/hip_runtime.h>
#include <hip/hip_bf16.h>
#include <math.h>

#define NN   30000
#define NE   300000
#define ETOT 330000   // NE + NN self loops
#define NB   300
#define EMB  64
#define D1   256      // 4 heads * 64
#define H1   4
#define H3   6
#define O3   121
#define D3   726      // 6 * 121
#define PS3  736      // padded row stride (bf16 elems) for conv3 P, 16B-aligned
#define NCLS 10

typedef __attribute__((ext_vector_type(8))) short short8;
typedef __attribute__((ext_vector_type(4))) float floatx4;

static inline int ceil_div(int a, int b) { return (a + b - 1) / b; }

__device__ inline void split_bf16(float f, unsigned short& hi, unsigned short& lo) {
    __hip_bfloat16 h = __float2bfloat16(f);
    float fh = __bfloat162float(h);
    __hip_bfloat16 l = __float2bfloat16(f - fh);
    hi = __builtin_bit_cast(unsigned short, h);
    lo = __builtin_bit_cast(unsigned short, l);
}

__device__ inline float bf2f(unsigned short u) {
    return __builtin_bit_cast(float, (unsigned int)u << 16);
}

__device__ inline unsigned short f2bf(float f) {
    return __builtin_bit_cast(unsigned short, __float2bfloat16(f));
}

// ---------------- setup kernels ----------------

__global__ void zero_kernel(int* __restrict__ cnt, int* __restrict__ gs, int* __restrict__ ge,
                            float* __restrict__ G) {
    int i = blockIdx.x * blockDim.x + threadIdx.x;
    if (i < NN) cnt[i] = 0;
    if (i < NB) { gs[i] = 0; ge[i] = 0; }
    if (i < NB * O3) G[i] = 0.f;
}

// node encoder -> split bf16 directly (feeds gemm1 only)
__global__ void h0_kernel(const int* __restrict__ x, const int* __restrict__ dep,
                          const float* __restrict__ nemb, const float* __restrict__ demb,
                          unsigned short* __restrict__ hi, unsigned short* __restrict__ lo) {
    int i = blockIdx.x * blockDim.x + threadIdx.x;
    if (i >= NN * EMB) return;
    int n = i >> 6, d = i & 63;
    float v = nemb[x[n] * EMB + d] + demb[dep[n] * EMB + d];
    split_bf16(v, hi[i], lo[i]);
}

// weight [K x N] fp32 -> transposed split bf16 [N x K]
__global__ void convB_kernel(const float* __restrict__ W, unsigned short* __restrict__ bthi,
                             unsigned short* __restrict__ btlo, int K, int N) {
    int idx = blockIdx.x * blockDim.x + threadIdx.x;
    if (idx >= K * N) return;
    int k = idx / N, n = idx % N;
    unsigned short h, l;
    split_bf16(W[idx], h, l);
    bthi[n * K + k] = h;
    btlo[n * K + k] = l;
}

__global__ void count_kernel(const int* __restrict__ ei, int* __restrict__ cnt) {
    int e = blockIdx.x * blockDim.x + threadIdx.x;
    if (e >= ETOT) return;
    int dst = (e < NE) ? ei[NE + e] : (e - NE);
    atomicAdd(&cnt[dst], 1);
}

__global__ __launch_bounds__(1024) void scan_kernel(const int* __restrict__ cnt,
                                                    int* __restrict__ rowoff,
                                                    int* __restrict__ fillp) {
    __shared__ int buf[1024];
    __shared__ int carry;
    int tid = threadIdx.x;
    if (tid == 0) carry = 0;
    __syncthreads();
    for (int base = 0; base < NN; base += 1024) {
        int i = base + tid;
        int v = (i < NN) ? cnt[i] : 0;
        buf[tid] = v;
        __syncthreads();
        for (int off = 1; off < 1024; off <<= 1) {
            int t = (tid >= off) ? buf[tid - off] : 0;
            __syncthreads();
            buf[tid] += t;
            __syncthreads();
        }
        int incl = buf[tid];
        int c = carry;
        if (i < NN) {
            int excl = c + incl - v;
            rowoff[i] = excl;
            fillp[i]  = excl;
        }
        __syncthreads();
        if (tid == 0) carry = c + buf[1023];
        __syncthreads();
    }
    if (tid == 0) rowoff[NN] = carry;   // == ETOT
}

__global__ void fill_kernel(const int* __restrict__ ei, int* __restrict__ fillp,
                            int* __restrict__ csr) {
    int e = blockIdx.x * blockDim.x + threadIdx.x;
    if (e >= ETOT) return;
    int src, dst;
    if (e < NE) { src = ei[e]; dst = ei[NE + e]; }
    else        { src = e - NE; dst = e - NE; }
    int slot = atomicAdd(&fillp[dst], 1);
    csr[slot] = src;
}

__global__ void ranges_kernel(const int* __restrict__ batch, int* __restrict__ gs,
                              int* __restrict__ ge) {
    int n = blockIdx.x * blockDim.x + threadIdx.x;
    if (n >= NN) return;
    int b = batch[n];
    if (n == 0 || batch[n - 1] != b) gs[b] = n;
    if (n == NN - 1 || batch[n + 1] != b) ge[b] = n + 1;
}

// ---------------- MFMA GEMM: C[MxN](bf16) = A[MxK] * BT[NxK]^T, split-bf16 ----------------

#define LDA 40

__global__ __launch_bounds__(256) void gemm_mfma_kernel(
    const unsigned short* __restrict__ Ahi, const unsigned short* __restrict__ Alo,
    const unsigned short* __restrict__ Bhi, const unsigned short* __restrict__ Blo,
    unsigned short* __restrict__ C, int M, int K, int N, int PS) {
    __shared__ unsigned short sAh[128 * LDA], sAl[128 * LDA];
    __shared__ unsigned short sBh[128 * LDA], sBl[128 * LDA];
    int tid = threadIdx.x;
    int lane = tid & 63, wave = tid >> 6;
    int wr = (wave >> 1) * 64, wc = (wave & 1) * 64;
    int quad = lane >> 4, mr = lane & 15;
    int row0 = blockIdx.y * 128, col0 = blockIdx.x * 128;

    floatx4 zero = {0.f, 0.f, 0.f, 0.f};
    floatx4 acc[4][4];
    #pragma unroll
    for (int i = 0; i < 4; i++)
        #pragma unroll
        for (int j = 0; j < 4; j++) acc[i][j] = zero;

    for (int k0 = 0; k0 < K; k0 += 32) {
        #pragma unroll
        for (int ch = 0; ch < 2; ch++) {
            int linear = (ch * 256 + tid) * 8;   // 128*32 = 4096 elements
            int r = linear >> 5, c = linear & 31;
            uint4 vh, vl;
            int gr = row0 + r;
            if (gr < M) {
                vh = *(const uint4*)(Ahi + (size_t)gr * K + k0 + c);
                vl = *(const uint4*)(Alo + (size_t)gr * K + k0 + c);
            } else { vh = uint4{0, 0, 0, 0}; vl = uint4{0, 0, 0, 0}; }
            *(uint4*)&sAh[r * LDA + c] = vh;
            *(uint4*)&sAl[r * LDA + c] = vl;
            int gn = col0 + r;
            if (gn < N) {
                vh = *(const uint4*)(Bhi + (size_t)gn * K + k0 + c);
                vl = *(const uint4*)(Blo + (size_t)gn * K + k0 + c);
            } else { vh = uint4{0, 0, 0, 0}; vl = uint4{0, 0, 0, 0}; }
            *(uint4*)&sBh[r * LDA + c] = vh;
            *(uint4*)&sBl[r * LDA + c] = vl;
        }
        __syncthreads();

        short8 ah[4], al[4], bh[4], bl[4];
        #pragma unroll
        for (int i = 0; i < 4; i++) {
            int ar = wr + i * 16 + mr;
            ah[i] = *(const short8*)&sAh[ar * LDA + quad * 8];
            al[i] = *(const short8*)&sAl[ar * LDA + quad * 8];
            int br = wc + i * 16 + mr;
            bh[i] = *(const short8*)&sBh[br * LDA + quad * 8];
            bl[i] = *(const short8*)&sBl[br * LDA + quad * 8];
        }
        #pragma unroll
        for (int i = 0; i < 4; i++)
            #pragma unroll
            for (int j = 0; j < 4; j++) {
                acc[i][j] = __builtin_amdgcn_mfma_f32_16x16x32_bf16(ah[i], bh[j], acc[i][j], 0, 0, 0);
                acc[i][j] = __builtin_amdgcn_mfma_f32_16x16x32_bf16(ah[i], bl[j], acc[i][j], 0, 0, 0);
                acc[i][j] = __builtin_amdgcn_mfma_f32_16x16x32_bf16(al[i], bh[j], acc[i][j], 0, 0, 0);
            }
        __syncthreads();
    }

    #pragma unroll
    for (int i = 0; i < 4; i++) {
        #pragma unroll
        for (int j = 0; j < 4; j++) {
            int gc = col0 + wc + j * 16 + mr;
            if (gc >= N) continue;
            int gr0 = row0 + wr + i * 16 + quad * 4;
            #pragma unroll
            for (int r = 0; r < 4; r++) {
                int gr = gr0 + r;
                if (gr < M) C[(size_t)gr * PS + gc] = f2bf(acc[i][j][r]);
            }
        }
    }
}

// ---------------- attention logits (bf16 P) ----------------

template <int H, int D, int PS>
__global__ void logits_kernel(const unsigned short* __restrict__ P, const float* __restrict__ as_,
                              const float* __restrict__ ad_, float* __restrict__ es,
                              float* __restrict__ ed) {
    int idx = blockIdx.x * blockDim.x + threadIdx.x;
    if (idx >= NN * H) return;
    int node = idx / H, h = idx % H;
    const unsigned short* row = P + (size_t)node * PS + h * D;
    float s1 = 0.f, s2 = 0.f;
    #pragma unroll 4
    for (int d = 0; d < D; d++) {
        float v = bf2f(row[d]);
        s1 += v * as_[h * D + d];
        s2 += v * ad_[h * D + d];
    }
    es[idx] = s1;
    ed[idx] = s2;
}

// ---------------- edge softmax (per dst,head) ----------------

template <int H>
__global__ void edge_softmax_kernel(const float* __restrict__ es, const float* __restrict__ ed,
                                    const int* __restrict__ rowoff, const int* __restrict__ csr,
                                    float* __restrict__ exw, float* __restrict__ invs) {
    int idx = blockIdx.x * blockDim.x + threadIdx.x;
    if (idx >= NN * H) return;
    int node = idx / H, h = idx % H;
    int s0 = rowoff[node], s1 = rowoff[node + 1];
    float edv = ed[idx];
    float mx = -3.4e38f;
    for (int s = s0; s < s1; s++) {
        int src = csr[s];
        float v = es[src * H + h] + edv;
        v = v > 0.f ? v : 0.2f * v;
        mx = fmaxf(mx, v);
    }
    float sum = 0.f;
    for (int s = s0; s < s1; s++) {
        int src = csr[s];
        float v = es[src * H + h] + edv;
        v = v > 0.f ? v : 0.2f * v;
        float ex = expf(v - mx);
        exw[s * H + h] = ex;
        sum += ex;
    }
    invs[idx] = 1.f / (sum + 1e-16f);
}

// ---------------- conv1/2 aggregation: one wave per dst, bf16 gather ----------------
// F=256: each lane owns 4 consecutive features (one ushort4 = full 512B row/wave).

__global__ __launch_bounds__(256) void aggregate12_kernel(
    const unsigned short* __restrict__ P, const float* __restrict__ exw,
    const float* __restrict__ invs, const int* __restrict__ rowoff,
    const int* __restrict__ csr, const float* __restrict__ bias,
    unsigned short* __restrict__ outHi, unsigned short* __restrict__ outLo) {
    int wave = threadIdx.x >> 6, lane = threadIdx.x & 63;
    int dst = blockIdx.x * 4 + wave;           // grid exact: NN/4 blocks
    int head = lane >> 4;                      // 64 feat / head
    float inv = invs[dst * 4 + head];
    float acc0 = 0.f, acc1 = 0.f, acc2 = 0.f, acc3 = 0.f;
    int s0 = rowoff[dst], s1 = rowoff[dst + 1];
    for (int s = s0; s < s1; s++) {
        int src = csr[s];
        ushort4 v = *(const ushort4*)(P + (size_t)src * D1 + lane * 4);
        float w = exw[s * 4 + head] * inv;
        acc0 += w * bf2f(v.x);
        acc1 += w * bf2f(v.y);
        acc2 += w * bf2f(v.z);
        acc3 += w * bf2f(v.w);
    }
    int f0 = lane * 4;
    float a[4] = {acc0, acc1, acc2, acc3};
    ushort4 hi4, lo4;
    unsigned short hh, ll;
    #pragma unroll
    for (int e = 0; e < 4; e++) {
        float v = a[e] + bias[f0 + e];
        v = v > 0.f ? v : expm1f(v);
        split_bf16(v, hh, ll);
        if (e == 0) { hi4.x = hh; lo4.x = ll; }
        else if (e == 1) { hi4.y = hh; lo4.y = ll; }
        else if (e == 2) { hi4.z = hh; lo4.z = ll; }
        else { hi4.w = hh; lo4.w = ll; }
    }
    *(ushort4*)(outHi + (size_t)dst * D1 + f0) = hi4;
    *(ushort4*)(outLo + (size_t)dst * D1 + f0) = lo4;
}

// ---------------- conv3 aggregation fused with pooling ----------------
// One wave per dst: gather bf16 rows (stride PS3), weight by alpha, head-sum
// 726 -> 121 via LDS, atomicAdd into per-graph accumulator G[NB][121].

__global__ __launch_bounds__(256) void aggregate3_kernel(
    const unsigned short* __restrict__ P, const float* __restrict__ exw,
    const float* __restrict__ invs, const int* __restrict__ rowoff,
    const int* __restrict__ csr, const int* __restrict__ batch,
    float* __restrict__ G) {
    __shared__ float sh[4][D3];
    int wave = threadIdx.x >> 6, lane = threadIdx.x & 63;
    int dst = blockIdx.x * 4 + wave;           // grid exact: NN/4 blocks
    int b = batch[dst];
    // per-lane element heads + validity for 3 chunks x 4 elems
    int hh[3][4];
    bool val[3][4];
    #pragma unroll
    for (int ch = 0; ch < 3; ch++)
        #pragma unroll
        for (int e = 0; e < 4; e++) {
            int f = ch * 256 + lane * 4 + e;
            val[ch][e] = (f < D3);
            hh[ch][e] = val[ch][e] ? (f / O3) : 0;
        }
    float invv = (lane < H3) ? invs[dst * H3 + lane] : 0.f;
    float acc[3][4] = {};
    int s0 = rowoff[dst], s1 = rowoff[dst + 1];
    for (int s = s0; s < s1; s++) {
        int src = csr[s];
        float aw = (lane < H3) ? exw[s * H3 + lane] * invv : 0.f;
        #pragma unroll
        for (int ch = 0; ch < 3; ch++) {
            ushort4 v = *(const ushort4*)(P + (size_t)src * PS3 + ch * 256 + lane * 4);
            float w0 = val[ch][0] ? __shfl(aw, hh[ch][0]) : 0.f;
            float w1 = val[ch][1] ? __shfl(aw, hh[ch][1]) : 0.f;
            float w2 = val[ch][2] ? __shfl(aw, hh[ch][2]) : 0.f;
            float w3 = val[ch][3] ? __shfl(aw, hh[ch][3]) : 0.f;
            acc[ch][0] += w0 * bf2f(v.x);
            acc[ch][1] += w1 * bf2f(v.y);
            acc[ch][2] += w2 * bf2f(v.z);
            acc[ch][3] += w3 * bf2f(v.w);
        }
    }
    #pragma unroll
    for (int ch = 0; ch < 3; ch++)
        #pragma unroll
        for (int e = 0; e < 4; e++) {
            int f = ch * 256 + lane * 4 + e;
            if (f < D3) sh[wave][f] = acc[ch][e];
        }
    __syncthreads();
    #pragma unroll
    for (int rep = 0; rep < 2; rep++) {
        int k = rep * 64 + lane;
        if (k < O3) {
            float y = 0.f;
            #pragma unroll
            for (int h = 0; h < H3; h++) y += sh[wave][h * O3 + k];
            atomicAdd(&G[b * O3 + k], y);
        }
    }
}

// ---------------- final: per-graph mean + head-mean bias + classifier ----------------

__global__ __launch_bounds__(128) void final_kernel(
    const float* __restrict__ G, const int* __restrict__ gs, const int* __restrict__ ge,
    const float* __restrict__ b3, const float* __restrict__ wp,
    const float* __restrict__ bp, float* __restrict__ out) {
    __shared__ float g[O3];
    int b = blockIdx.x, tid = threadIdx.x;
    int cntn = ge[b] - gs[b];
    if (tid < O3) {
        if (cntn > 0) {
            float bs = 0.f;
            #pragma unroll
            for (int h = 0; h < H3; h++) bs += b3[h * O3 + tid];
            g[tid] = G[b * O3 + tid] / (6.f * (float)cntn) + bs * (1.f / 6.f);
        } else {
            g[tid] = 0.f;
        }
    }
    __syncthreads();
    if (tid < NCLS) {
        float o = bp[tid];
        for (int k = 0; k < O3; k++) o += g[k] * wp[k * NCLS + tid];
        out[b * NCLS + tid] = o;
    }
}

// ---------------- launch ----------------

extern "C" void kernel_launch(void* const* d_in, const int* in_sizes, int n_in,
                              void* d_out, int out_size, void* d_ws, size_t ws_size,
                              hipStream_t stream) {
    const int* x     = (const int*)d_in[0];
    const int* dep   = (const int*)d_in[1];
    const int* ei    = (const int*)d_in[2];
    const int* batch = (const int*)d_in[3];
    const float* nemb = (const float*)d_in[4];
    const float* demb = (const float*)d_in[5];
    const float* w1  = (const float*)d_in[6];
    const float* as1 = (const float*)d_in[7];
    const float* ad1 = (const float*)d_in[8];
    const float* b1  = (const float*)d_in[9];
    const float* w2  = (const float*)d_in[10];
    const float* as2 = (const float*)d_in[11];
    const float* ad2 = (const float*)d_in[12];
    const float* b2  = (const float*)d_in[13];
    const float* w3  = (const float*)d_in[14];
    const float* as3 = (const float*)d_in[15];
    const float* ad3 = (const float*)d_in[16];
    const float* b3  = (const float*)d_in[17];
    const float* wp  = (const float*)d_in[18];
    const float* bp  = (const float*)d_in[19];
    float* out = (float*)d_out;

    char* ws = (char*)d_ws;
    size_t off = 0;
    auto alloc = [&](size_t bytes) -> void* {
        void* p = ws + off;
        off += (bytes + 255) & ~(size_t)255;
        return p;
    };
    unsigned short* Hhi = (unsigned short*)alloc((size_t)NN * D1 * 2);
    unsigned short* Hlo = (unsigned short*)alloc((size_t)NN * D1 * 2);
    unsigned short* Whi = (unsigned short*)alloc((size_t)D3 * D1 * 2);
    unsigned short* Wlo = (unsigned short*)alloc((size_t)D3 * D1 * 2);
    unsigned short* Pb  = (unsigned short*)alloc(((size_t)NN * PS3 + 1024) * 2);  // bf16 P (+overrun pad)
    float* G    = (float*)alloc((size_t)NB * O3 * 4);
    float* es   = (float*)alloc((size_t)NN * 6 * 4);
    float* ed   = (float*)alloc((size_t)NN * 6 * 4);
    float* invs = (float*)alloc((size_t)NN * 6 * 4);
    float* exw  = (float*)alloc((size_t)ETOT * 6 * 4);
    int* cnt    = (int*)alloc((size_t)NN * 4);
    int* rowoff = (int*)alloc((size_t)(NN + 1) * 4);
    int* fillp  = (int*)alloc((size_t)NN * 4);
    int* csr    = (int*)alloc((size_t)ETOT * 4);
    int* gs     = (int*)alloc((size_t)NB * 4);
    int* ge     = (int*)alloc((size_t)NB * 4);

    // --- graph preprocessing ---
    zero_kernel<<<ceil_div(NB * O3 + 256, 256), 256, 0, stream>>>(cnt, gs, ge, G);
    h0_kernel<<<ceil_div(NN * EMB, 256), 256, 0, stream>>>(x, dep, nemb, demb, Hhi, Hlo);
    count_kernel<<<ceil_div(ETOT, 256), 256, 0, stream>>>(ei, cnt);
    scan_kernel<<<1, 1024, 0, stream>>>(cnt, rowoff, fillp);
    fill_kernel<<<ceil_div(ETOT, 256), 256, 0, stream>>>(ei, fillp, csr);
    ranges_kernel<<<ceil_div(NN, 256), 256, 0, stream>>>(batch, gs, ge);

    // --- conv1: [NN,64] -> [NN,256], 4 heads x 64 ---
    convB_kernel<<<ceil_div(EMB * D1, 256), 256, 0, stream>>>(w1, Whi, Wlo, EMB, D1);
    gemm_mfma_kernel<<<dim3(ceil_div(D1, 128), ceil_div(NN, 128)), 256, 0, stream>>>(
        Hhi, Hlo, Whi, Wlo, Pb, NN, EMB, D1, D1);
    logits_kernel<H1, EMB, D1><<<ceil_div(NN * H1, 256), 256, 0, stream>>>(Pb, as1, ad1, es, ed);
    edge_softmax_kernel<H1><<<ceil_div(NN * H1, 256), 256, 0, stream>>>(es, ed, rowoff, csr, exw, invs);
    aggregate12_kernel<<<NN / 4, 256, 0, stream>>>(Pb, exw, invs, rowoff, csr, b1, Hhi, Hlo);

    // --- conv2: [NN,256] -> [NN,256] ---
    convB_kernel<<<ceil_div(D1 * D1, 256), 256, 0, stream>>>(w2, Whi, Wlo, D1, D1);
    gemm_mfma_kernel<<<dim3(ceil_div(D1, 128), ceil_div(NN, 128)), 256, 0, stream>>>(
        Hhi, Hlo, Whi, Wlo, Pb, NN, D1, D1, D1);
    logits_kernel<H1, EMB, D1><<<ceil_div(NN * H1, 256), 256, 0, stream>>>(Pb, as2, ad2, es, ed);
    edge_softmax_kernel<H1><<<ceil_div(NN * H1, 256), 256, 0, stream>>>(es, ed, rowoff, csr, exw, invs);
    aggregate12_kernel<<<NN / 4, 256, 0, stream>>>(Pb, exw, invs, rowoff, csr, b2, Hhi, Hlo);

    // --- conv3: [NN,256] -> [NN,726], 6 heads x 121, fused with pooling ---
    convB_kernel<<<ceil_div(D1 * D3, 256), 256, 0, stream>>>(w3, Whi, Wlo, D1, D3);
    gemm_mfma_kernel<<<dim3(ceil_div(D3, 128), ceil_div(NN, 128)), 256, 0, stream>>>(
        Hhi, Hlo, Whi, Wlo, Pb, NN, D1, D3, PS3);
    logits_kernel<H3, O3, PS3><<<ceil_div(NN * H3, 256), 256, 0, stream>>>(Pb, as3, ad3, es, ed);
    edge_softmax_kernel<H3><<<ceil_div(NN * H3, 256), 256, 0, stream>>>(es, ed, rowoff, csr, exw, invs);
    aggregate3_kernel<<<NN / 4, 256, 0, stream>>>(Pb, exw, invs, rowoff, csr, batch, G);

    // --- final classifier ---
    final_kernel<<<NB, 128, 0, stream>>>(G, gs, ge, b3, wp, bp, out);
}

// Round 4
// 481.015 us; speedup vs baseline: 2.2690x; 1.2491x over previous
//
#include <hip/hip_runtime.h>
#include <hip/hip_bf16.h>
#include <math.h>

#define NN   30000
#define NE   300000
#define ETOT 330000   // NE + NN self loops
#define NB   300
#define EMB  64
#define D1   256      // 4 heads * 64
#define H1   4
#define H3   6
#define O3   121
#define D3   726      // 6 * 121
#define NQ   60       // 6 heads x 10 classes (pre-projected conv3 output)
#define N3   72       // NQ + 6 (es) + 6 (ed)
#define NCLS 10

typedef __attribute__((ext_vector_type(8))) short short8;
typedef __attribute__((ext_vector_type(4))) float floatx4;

static inline int ceil_div(int a, int b) { return (a + b - 1) / b; }

__device__ inline void split_bf16(float f, unsigned short& hi, unsigned short& lo) {
    __hip_bfloat16 h = __float2bfloat16(f);
    float fh = __bfloat162float(h);
    __hip_bfloat16 l = __float2bfloat16(f - fh);
    hi = __builtin_bit_cast(unsigned short, h);
    lo = __builtin_bit_cast(unsigned short, l);
}

__device__ inline float bf2f(unsigned short u) {
    return __builtin_bit_cast(float, (unsigned int)u << 16);
}

__device__ inline unsigned short f2bf(float f) {
    return __builtin_bit_cast(unsigned short, __float2bfloat16(f));
}

// ---------------- setup kernels ----------------

__global__ void zero_kernel(int* __restrict__ cnt, int* __restrict__ gs, int* __restrict__ ge,
                            float* __restrict__ G) {
    int i = blockIdx.x * blockDim.x + threadIdx.x;
    if (i < NN) cnt[i] = 0;
    if (i < NB) { gs[i] = 0; ge[i] = 0; }
    if (i < NB * NCLS) G[i] = 0.f;
}

__global__ void h0_kernel(const int* __restrict__ x, const int* __restrict__ dep,
                          const float* __restrict__ nemb, const float* __restrict__ demb,
                          unsigned short* __restrict__ hi, unsigned short* __restrict__ lo) {
    int i = blockIdx.x * blockDim.x + threadIdx.x;
    if (i >= NN * EMB) return;
    int n = i >> 6, d = i & 63;
    float v = nemb[x[n] * EMB + d] + demb[dep[n] * EMB + d];
    split_bf16(v, hi[i], lo[i]);
}

// weight [K x N] fp32 -> transposed split bf16 [N x K]
__global__ void convB_kernel(const float* __restrict__ W, unsigned short* __restrict__ bthi,
                             unsigned short* __restrict__ btlo, int K, int N) {
    int idx = blockIdx.x * blockDim.x + threadIdx.x;
    if (idx >= K * N) return;
    int k = idx / N, n = idx % N;
    unsigned short h, l;
    split_bf16(W[idx], h, l);
    bthi[n * K + k] = h;
    btlo[n * K + k] = l;
}

// conv3 folded weight: BT[72][256] = [w3*blockdiag(wp) | w3*as3 | w3*ad3]^T, split bf16
__global__ void prep3_kernel(const float* __restrict__ w3, const float* __restrict__ as3,
                             const float* __restrict__ ad3, const float* __restrict__ wp,
                             unsigned short* __restrict__ bthi, unsigned short* __restrict__ btlo) {
    int idx = blockIdx.x * blockDim.x + threadIdx.x;
    if (idx >= N3 * D1) return;
    int n = idx / D1, k = idx % D1;
    float acc = 0.f;
    if (n < NQ) {
        int h = n / NCLS, c = n % NCLS;
        const float* wrow = w3 + (size_t)k * D3 + h * O3;
        for (int j = 0; j < O3; j++) acc += wrow[j] * wp[j * NCLS + c];
    } else if (n < NQ + H3) {
        int h = n - NQ;
        const float* wrow = w3 + (size_t)k * D3 + h * O3;
        for (int j = 0; j < O3; j++) acc += wrow[j] * as3[h * O3 + j];
    } else {
        int h = n - NQ - H3;
        const float* wrow = w3 + (size_t)k * D3 + h * O3;
        for (int j = 0; j < O3; j++) acc += wrow[j] * ad3[h * O3 + j];
    }
    unsigned short h16, l16;
    split_bf16(acc, h16, l16);
    bthi[idx] = h16;
    btlo[idx] = l16;
}

__global__ void count_kernel(const int* __restrict__ ei, int* __restrict__ cnt) {
    int e = blockIdx.x * blockDim.x + threadIdx.x;
    if (e >= ETOT) return;
    int dst = (e < NE) ? ei[NE + e] : (e - NE);
    atomicAdd(&cnt[dst], 1);
}

__global__ __launch_bounds__(1024) void scan_kernel(const int* __restrict__ cnt,
                                                    int* __restrict__ rowoff,
                                                    int* __restrict__ fillp) {
    __shared__ int buf[1024];
    __shared__ int carry;
    int tid = threadIdx.x;
    if (tid == 0) carry = 0;
    __syncthreads();
    for (int base = 0; base < NN; base += 1024) {
        int i = base + tid;
        int v = (i < NN) ? cnt[i] : 0;
        buf[tid] = v;
        __syncthreads();
        for (int off = 1; off < 1024; off <<= 1) {
            int t = (tid >= off) ? buf[tid - off] : 0;
            __syncthreads();
            buf[tid] += t;
            __syncthreads();
        }
        int incl = buf[tid];
        int c = carry;
        if (i < NN) {
            int excl = c + incl - v;
            rowoff[i] = excl;
            fillp[i]  = excl;
        }
        __syncthreads();
        if (tid == 0) carry = c + buf[1023];
        __syncthreads();
    }
    if (tid == 0) rowoff[NN] = carry;   // == ETOT
}

__global__ void fill_kernel(const int* __restrict__ ei, int* __restrict__ fillp,
                            int* __restrict__ csr) {
    int e = blockIdx.x * blockDim.x + threadIdx.x;
    if (e >= ETOT) return;
    int src, dst;
    if (e < NE) { src = ei[e]; dst = ei[NE + e]; }
    else        { src = e - NE; dst = e - NE; }
    int slot = atomicAdd(&fillp[dst], 1);
    csr[slot] = src;
}

__global__ void ranges_kernel(const int* __restrict__ batch, int* __restrict__ gs,
                              int* __restrict__ ge) {
    int n = blockIdx.x * blockDim.x + threadIdx.x;
    if (n >= NN) return;
    int b = batch[n];
    if (n == 0 || batch[n - 1] != b) gs[b] = n;
    if (n == NN - 1 || batch[n + 1] != b) ge[b] = n + 1;
}

// ---------------- MFMA GEMM: C[MxN] = A[MxK] * BT[NxK]^T, split-bf16 ----------------
// MODE 0: bf16 output, stride PS.  MODE 1: fp32 Q[.,60] + es[.,6] + ed[.,6].

#define LDA 40

template <int MODE>
__global__ __launch_bounds__(256) void gemm_mfma_kernel(
    const unsigned short* __restrict__ Ahi, const unsigned short* __restrict__ Alo,
    const unsigned short* __restrict__ Bhi, const unsigned short* __restrict__ Blo,
    unsigned short* __restrict__ Cbf, float* __restrict__ Cq,
    float* __restrict__ es, float* __restrict__ ed,
    int M, int K, int N, int PS) {
    __shared__ unsigned short sAh[128 * LDA], sAl[128 * LDA];
    __shared__ unsigned short sBh[128 * LDA], sBl[128 * LDA];
    int tid = threadIdx.x;
    int lane = tid & 63, wave = tid >> 6;
    int wr = (wave >> 1) * 64, wc = (wave & 1) * 64;
    int quad = lane >> 4, mr = lane & 15;
    int row0 = blockIdx.y * 128, col0 = blockIdx.x * 128;

    floatx4 zero = {0.f, 0.f, 0.f, 0.f};
    floatx4 acc[4][4];
    #pragma unroll
    for (int i = 0; i < 4; i++)
        #pragma unroll
        for (int j = 0; j < 4; j++) acc[i][j] = zero;

    for (int k0 = 0; k0 < K; k0 += 32) {
        #pragma unroll
        for (int ch = 0; ch < 2; ch++) {
            int linear = (ch * 256 + tid) * 8;   // 128*32 = 4096 elements
            int r = linear >> 5, c = linear & 31;
            uint4 vh, vl;
            int gr = row0 + r;
            if (gr < M) {
                vh = *(const uint4*)(Ahi + (size_t)gr * K + k0 + c);
                vl = *(const uint4*)(Alo + (size_t)gr * K + k0 + c);
            } else { vh = uint4{0, 0, 0, 0}; vl = uint4{0, 0, 0, 0}; }
            *(uint4*)&sAh[r * LDA + c] = vh;
            *(uint4*)&sAl[r * LDA + c] = vl;
            int gn = col0 + r;
            if (gn < N) {
                vh = *(const uint4*)(Bhi + (size_t)gn * K + k0 + c);
                vl = *(const uint4*)(Blo + (size_t)gn * K + k0 + c);
            } else { vh = uint4{0, 0, 0, 0}; vl = uint4{0, 0, 0, 0}; }
            *(uint4*)&sBh[r * LDA + c] = vh;
            *(uint4*)&sBl[r * LDA + c] = vl;
        }
        __syncthreads();

        short8 ah[4], al[4], bh[4], bl[4];
        #pragma unroll
        for (int i = 0; i < 4; i++) {
            int ar = wr + i * 16 + mr;
            ah[i] = *(const short8*)&sAh[ar * LDA + quad * 8];
            al[i] = *(const short8*)&sAl[ar * LDA + quad * 8];
            int br = wc + i * 16 + mr;
            bh[i] = *(const short8*)&sBh[br * LDA + quad * 8];
            bl[i] = *(const short8*)&sBl[br * LDA + quad * 8];
        }
        #pragma unroll
        for (int i = 0; i < 4; i++)
            #pragma unroll
            for (int j = 0; j < 4; j++) {
                acc[i][j] = __builtin_amdgcn_mfma_f32_16x16x32_bf16(ah[i], bh[j], acc[i][j], 0, 0, 0);
                acc[i][j] = __builtin_amdgcn_mfma_f32_16x16x32_bf16(ah[i], bl[j], acc[i][j], 0, 0, 0);
                acc[i][j] = __builtin_amdgcn_mfma_f32_16x16x32_bf16(al[i], bh[j], acc[i][j], 0, 0, 0);
            }
        __syncthreads();
    }

    #pragma unroll
    for (int i = 0; i < 4; i++) {
        #pragma unroll
        for (int j = 0; j < 4; j++) {
            int gc = col0 + wc + j * 16 + mr;
            if (gc >= N) continue;
            int gr0 = row0 + wr + i * 16 + quad * 4;
            #pragma unroll
            for (int r = 0; r < 4; r++) {
                int gr = gr0 + r;
                if (gr >= M) continue;
                float v = acc[i][j][r];
                if (MODE == 0) {
                    Cbf[(size_t)gr * PS + gc] = f2bf(v);
                } else {
                    if (gc < NQ)            Cq[(size_t)gr * NQ + gc] = v;
                    else if (gc < NQ + H3)  es[(size_t)gr * H3 + (gc - NQ)] = v;
                    else                    ed[(size_t)gr * H3 + (gc - NQ - H3)] = v;
                }
            }
        }
    }
}

// ---------------- attention logits (bf16 P), conv1/2 only ----------------

template <int H, int D, int PS>
__global__ void logits_kernel(const unsigned short* __restrict__ P, const float* __restrict__ as_,
                              const float* __restrict__ ad_, float* __restrict__ es,
                              float* __restrict__ ed) {
    int idx = blockIdx.x * blockDim.x + threadIdx.x;
    if (idx >= NN * H) return;
    int node = idx / H, h = idx % H;
    const unsigned short* row = P + (size_t)node * PS + h * D;
    float s1 = 0.f, s2 = 0.f;
    #pragma unroll 4
    for (int d = 0; d < D; d++) {
        float v = bf2f(row[d]);
        s1 += v * as_[h * D + d];
        s2 += v * ad_[h * D + d];
    }
    es[idx] = s1;
    ed[idx] = s2;
}

// ---------------- edge softmax (per dst,head) ----------------

template <int H>
__global__ void edge_softmax_kernel(const float* __restrict__ es, const float* __restrict__ ed,
                                    const int* __restrict__ rowoff, const int* __restrict__ csr,
                                    float* __restrict__ exw, float* __restrict__ invs) {
    int idx = blockIdx.x * blockDim.x + threadIdx.x;
    if (idx >= NN * H) return;
    int node = idx / H, h = idx % H;
    int s0 = rowoff[node], s1 = rowoff[node + 1];
    float edv = ed[idx];
    float mx = -3.4e38f;
    for (int s = s0; s < s1; s++) {
        int src = csr[s];
        float v = es[src * H + h] + edv;
        v = v > 0.f ? v : 0.2f * v;
        mx = fmaxf(mx, v);
    }
    float sum = 0.f;
    for (int s = s0; s < s1; s++) {
        int src = csr[s];
        float v = es[src * H + h] + edv;
        v = v > 0.f ? v : 0.2f * v;
        float ex = expf(v - mx);
        exw[s * H + h] = ex;
        sum += ex;
    }
    invs[idx] = 1.f / (sum + 1e-16f);
}

// ---------------- conv1/2 aggregation: one wave per dst, bf16 gather ----------------

__global__ __launch_bounds__(256) void aggregate12_kernel(
    const unsigned short* __restrict__ P, const float* __restrict__ exw,
    const float* __restrict__ invs, const int* __restrict__ rowoff,
    const int* __restrict__ csr, const float* __restrict__ bias,
    unsigned short* __restrict__ outHi, unsigned short* __restrict__ outLo) {
    int wave = threadIdx.x >> 6, lane = threadIdx.x & 63;
    int dst = blockIdx.x * 4 + wave;           // grid exact: NN/4 blocks
    int head = lane >> 4;                      // 64 feat / head
    float inv = invs[dst * 4 + head];
    float acc0 = 0.f, acc1 = 0.f, acc2 = 0.f, acc3 = 0.f;
    int s0 = rowoff[dst], s1 = rowoff[dst + 1];
    for (int s = s0; s < s1; s++) {
        int src = csr[s];
        ushort4 v = *(const ushort4*)(P + (size_t)src * D1 + lane * 4);
        float w = exw[s * 4 + head] * inv;
        acc0 += w * bf2f(v.x);
        acc1 += w * bf2f(v.y);
        acc2 += w * bf2f(v.z);
        acc3 += w * bf2f(v.w);
    }
    int f0 = lane * 4;
    float a[4] = {acc0, acc1, acc2, acc3};
    ushort4 hi4, lo4;
    unsigned short hh, ll;
    #pragma unroll
    for (int e = 0; e < 4; e++) {
        float v = a[e] + bias[f0 + e];
        v = v > 0.f ? v : expm1f(v);
        split_bf16(v, hh, ll);
        if (e == 0) { hi4.x = hh; lo4.x = ll; }
        else if (e == 1) { hi4.y = hh; lo4.y = ll; }
        else if (e == 2) { hi4.z = hh; lo4.z = ll; }
        else { hi4.w = hh; lo4.w = ll; }
    }
    *(ushort4*)(outHi + (size_t)dst * D1 + f0) = hi4;
    *(ushort4*)(outLo + (size_t)dst * D1 + f0) = lo4;
}

// ---------------- conv3: gather pre-projected Q rows, fused pool+classify accum ----------------
// One wave per dst. lane<60 -> (h,c); alpha-weighted sum of Q[src], head-sum -> 10,
// atomicAdd into G[b][10].

__global__ __launch_bounds__(256) void aggregate3q_kernel(
    const float* __restrict__ Q, const float* __restrict__ exw,
    const float* __restrict__ invs, const int* __restrict__ rowoff,
    const int* __restrict__ csr, const int* __restrict__ batch,
    float* __restrict__ G) {
    int wave = threadIdx.x >> 6, lane = threadIdx.x & 63;
    int dst = blockIdx.x * 4 + wave;           // grid exact: NN/4 blocks
    bool act = lane < NQ;
    int h = lane / NCLS;                       // valid for act
    float inv = act ? invs[dst * H3 + h] : 0.f;
    float acc = 0.f;
    int s0 = rowoff[dst], s1 = rowoff[dst + 1];
    for (int s = s0; s < s1; s++) {
        int src = csr[s];
        float w = act ? exw[s * H3 + h] * inv : 0.f;
        acc += w * Q[(size_t)src * NQ + (act ? lane : 0)];
    }
    // head-sum: lanes c, c+10, ..., c+50
    float tot = acc;
    #pragma unroll
    for (int h2 = 1; h2 < H3; h2++) tot += __shfl(acc, lane + h2 * NCLS);
    if (lane < NCLS) atomicAdd(&G[batch[dst] * NCLS + lane], tot);
}

// ---------------- final: per-graph mean + folded b3 bias + bp ----------------

__global__ __launch_bounds__(64) void final_kernel(
    const float* __restrict__ G, const int* __restrict__ gs, const int* __restrict__ ge,
    const float* __restrict__ b3, const float* __restrict__ wp,
    const float* __restrict__ bp, float* __restrict__ out) {
    int b = blockIdx.x, tid = threadIdx.x;
    if (tid >= NCLS) return;
    int cntn = ge[b] - gs[b];
    float o = bp[tid];
    if (cntn > 0) {
        // bias3 term: mean over heads of b3, projected through wp
        float bt = 0.f;
        for (int k = 0; k < O3; k++) {
            float bs = 0.f;
            #pragma unroll
            for (int h = 0; h < H3; h++) bs += b3[h * O3 + k];
            bt += bs * wp[k * NCLS + tid];
        }
        o += G[b * NCLS + tid] / (6.f * (float)cntn) + bt * (1.f / 6.f);
    }
    out[b * NCLS + tid] = o;
}

// ---------------- launch ----------------

extern "C" void kernel_launch(void* const* d_in, const int* in_sizes, int n_in,
                              void* d_out, int out_size, void* d_ws, size_t ws_size,
                              hipStream_t stream) {
    const int* x     = (const int*)d_in[0];
    const int* dep   = (const int*)d_in[1];
    const int* ei    = (const int*)d_in[2];
    const int* batch = (const int*)d_in[3];
    const float* nemb = (const float*)d_in[4];
    const float* demb = (const float*)d_in[5];
    const float* w1  = (const float*)d_in[6];
    const float* as1 = (const float*)d_in[7];
    const float* ad1 = (const float*)d_in[8];
    const float* b1  = (const float*)d_in[9];
    const float* w2  = (const float*)d_in[10];
    const float* as2 = (const float*)d_in[11];
    const float* ad2 = (const float*)d_in[12];
    const float* b2  = (const float*)d_in[13];
    const float* w3  = (const float*)d_in[14];
    const float* as3 = (const float*)d_in[15];
    const float* ad3 = (const float*)d_in[16];
    const float* b3  = (const float*)d_in[17];
    const float* wp  = (const float*)d_in[18];
    const float* bp  = (const float*)d_in[19];
    float* out = (float*)d_out;

    char* ws = (char*)d_ws;
    size_t off = 0;
    auto alloc = [&](size_t bytes) -> void* {
        void* p = ws + off;
        off += (bytes + 255) & ~(size_t)255;
        return p;
    };
    unsigned short* Hhi = (unsigned short*)alloc((size_t)NN * D1 * 2);
    unsigned short* Hlo = (unsigned short*)alloc((size_t)NN * D1 * 2);
    unsigned short* Whi = (unsigned short*)alloc((size_t)D1 * D1 * 2);
    unsigned short* Wlo = (unsigned short*)alloc((size_t)D1 * D1 * 2);
    unsigned short* Pb  = (unsigned short*)alloc((size_t)NN * D1 * 2);      // bf16 P (conv1/2)
    float* Q    = (float*)alloc(((size_t)NN * NQ + 64) * 4);                // conv3 pre-projected
    float* G    = (float*)alloc((size_t)NB * NCLS * 4);
    float* es   = (float*)alloc((size_t)NN * 6 * 4);
    float* ed   = (float*)alloc((size_t)NN * 6 * 4);
    float* invs = (float*)alloc((size_t)NN * 6 * 4);
    float* exw  = (float*)alloc((size_t)ETOT * 6 * 4);
    int* cnt    = (int*)alloc((size_t)NN * 4);
    int* rowoff = (int*)alloc((size_t)(NN + 1) * 4);
    int* fillp  = (int*)alloc((size_t)NN * 4);
    int* csr    = (int*)alloc((size_t)ETOT * 4);
    int* gs     = (int*)alloc((size_t)NB * 4);
    int* ge     = (int*)alloc((size_t)NB * 4);

    // --- graph preprocessing ---
    zero_kernel<<<ceil_div(NN, 256), 256, 0, stream>>>(cnt, gs, ge, G);
    h0_kernel<<<ceil_div(NN * EMB, 256), 256, 0, stream>>>(x, dep, nemb, demb, Hhi, Hlo);
    count_kernel<<<ceil_div(ETOT, 256), 256, 0, stream>>>(ei, cnt);
    scan_kernel<<<1, 1024, 0, stream>>>(cnt, rowoff, fillp);
    fill_kernel<<<ceil_div(ETOT, 256), 256, 0, stream>>>(ei, fillp, csr);
    ranges_kernel<<<ceil_div(NN, 256), 256, 0, stream>>>(batch, gs, ge);

    // --- conv1: [NN,64] -> [NN,256], 4 heads x 64 ---
    convB_kernel<<<ceil_div(EMB * D1, 256), 256, 0, stream>>>(w1, Whi, Wlo, EMB, D1);
    gemm_mfma_kernel<0><<<dim3(2, ceil_div(NN, 128)), 256, 0, stream>>>(
        Hhi, Hlo, Whi, Wlo, Pb, nullptr, nullptr, nullptr, NN, EMB, D1, D1);
    logits_kernel<H1, EMB, D1><<<ceil_div(NN * H1, 256), 256, 0, stream>>>(Pb, as1, ad1, es, ed);
    edge_softmax_kernel<H1><<<ceil_div(NN * H1, 256), 256, 0, stream>>>(es, ed, rowoff, csr, exw, invs);
    aggregate12_kernel<<<NN / 4, 256, 0, stream>>>(Pb, exw, invs, rowoff, csr, b1, Hhi, Hlo);

    // --- conv2: [NN,256] -> [NN,256] ---
    convB_kernel<<<ceil_div(D1 * D1, 256), 256, 0, stream>>>(w2, Whi, Wlo, D1, D1);
    gemm_mfma_kernel<0><<<dim3(2, ceil_div(NN, 128)), 256, 0, stream>>>(
        Hhi, Hlo, Whi, Wlo, Pb, nullptr, nullptr, nullptr, NN, D1, D1, D1);
    logits_kernel<H1, EMB, D1><<<ceil_div(NN * H1, 256), 256, 0, stream>>>(Pb, as2, ad2, es, ed);
    edge_softmax_kernel<H1><<<ceil_div(NN * H1, 256), 256, 0, stream>>>(es, ed, rowoff, csr, exw, invs);
    aggregate12_kernel<<<NN / 4, 256, 0, stream>>>(Pb, exw, invs, rowoff, csr, b2, Hhi, Hlo);

    // --- conv3 folded: [NN,256] -> Q[NN,60] + es/ed[NN,6] ---
    prep3_kernel<<<ceil_div(N3 * D1, 256), 256, 0, stream>>>(w3, as3, ad3, wp, Whi, Wlo);
    gemm_mfma_kernel<1><<<dim3(1, ceil_div(NN, 128)), 256, 0, stream>>>(
        Hhi, Hlo, Whi, Wlo, nullptr, Q, es, ed, NN, D1, N3, 0);
    edge_softmax_kernel<H3><<<ceil_div(NN * H3, 256), 256, 0, stream>>>(es, ed, rowoff, csr, exw, invs);
    aggregate3q_kernel<<<NN / 4, 256, 0, stream>>>(Q, exw, invs, rowoff, csr, batch, G);

    // --- final classifier ---
    final_kernel<<<NB, 64, 0, stream>>>(G, gs, ge, b3, wp, bp, out);
}

// Round 5
// 462.033 us; speedup vs baseline: 2.3622x; 1.0411x over previous
//
#include <hip/hip_runtime.h>
#include <hip/hip_bf16.h>
#include <math.h>

#define NN   30000
#define NE   300000
#define ETOT 330000   // NE + NN self loops
#define NB   300
#define EMB  64
#define D1   256      // 4 heads * 64
#define H1   4
#define H3   6
#define O3   121
#define D3   726      // 6 * 121
#define NQ   60       // 6 heads x 10 classes (pre-projected conv3 output)
#define N3   72       // NQ + 6 (es) + 6 (ed)
#define NCLS 10

typedef __attribute__((ext_vector_type(8))) short short8;
typedef __attribute__((ext_vector_type(4))) float floatx4;

static inline int ceil_div(int a, int b) { return (a + b - 1) / b; }

__device__ inline void split_bf16(float f, unsigned short& hi, unsigned short& lo) {
    __hip_bfloat16 h = __float2bfloat16(f);
    float fh = __bfloat162float(h);
    __hip_bfloat16 l = __float2bfloat16(f - fh);
    hi = __builtin_bit_cast(unsigned short, h);
    lo = __builtin_bit_cast(unsigned short, l);
}

__device__ inline float bf2f(unsigned short u) {
    return __builtin_bit_cast(float, (unsigned int)u << 16);
}

__device__ inline unsigned short f2bf(float f) {
    return __builtin_bit_cast(unsigned short, __float2bfloat16(f));
}

// ---------------- setup kernels ----------------

__global__ void zero_kernel(int* __restrict__ cnt, int* __restrict__ gs, int* __restrict__ ge,
                            float* __restrict__ G) {
    int i = blockIdx.x * blockDim.x + threadIdx.x;
    if (i < NN) cnt[i] = 0;
    if (i < NB) { gs[i] = 0; ge[i] = 0; }
    if (i < NB * NCLS) G[i] = 0.f;
}

__global__ void h0_kernel(const int* __restrict__ x, const int* __restrict__ dep,
                          const float* __restrict__ nemb, const float* __restrict__ demb,
                          unsigned short* __restrict__ hi, unsigned short* __restrict__ lo) {
    int i = blockIdx.x * blockDim.x + threadIdx.x;
    if (i >= NN * EMB) return;
    int n = i >> 6, d = i & 63;
    float v = nemb[x[n] * EMB + d] + demb[dep[n] * EMB + d];
    split_bf16(v, hi[i], lo[i]);
}

// weight [K x N] fp32 -> transposed split bf16 [N x K]
__global__ void convB_kernel(const float* __restrict__ W, unsigned short* __restrict__ bthi,
                             unsigned short* __restrict__ btlo, int K, int N) {
    int idx = blockIdx.x * blockDim.x + threadIdx.x;
    if (idx >= K * N) return;
    int k = idx / N, n = idx % N;
    unsigned short h, l;
    split_bf16(W[idx], h, l);
    bthi[n * K + k] = h;
    btlo[n * K + k] = l;
}

// conv3 folded weight: BT[72][256] = [w3*blockdiag(wp) | w3*as3 | w3*ad3]^T, split bf16
__global__ void prep3_kernel(const float* __restrict__ w3, const float* __restrict__ as3,
                             const float* __restrict__ ad3, const float* __restrict__ wp,
                             unsigned short* __restrict__ bthi, unsigned short* __restrict__ btlo) {
    int idx = blockIdx.x * blockDim.x + threadIdx.x;
    if (idx >= N3 * D1) return;
    int n = idx / D1, k = idx % D1;
    float acc = 0.f;
    if (n < NQ) {
        int h = n / NCLS, c = n % NCLS;
        const float* wrow = w3 + (size_t)k * D3 + h * O3;
        for (int j = 0; j < O3; j++) acc += wrow[j] * wp[j * NCLS + c];
    } else if (n < NQ + H3) {
        int h = n - NQ;
        const float* wrow = w3 + (size_t)k * D3 + h * O3;
        for (int j = 0; j < O3; j++) acc += wrow[j] * as3[h * O3 + j];
    } else {
        int h = n - NQ - H3;
        const float* wrow = w3 + (size_t)k * D3 + h * O3;
        for (int j = 0; j < O3; j++) acc += wrow[j] * ad3[h * O3 + j];
    }
    unsigned short h16, l16;
    split_bf16(acc, h16, l16);
    bthi[idx] = h16;
    btlo[idx] = l16;
}

__global__ void count_kernel(const int* __restrict__ ei, int* __restrict__ cnt) {
    int e = blockIdx.x * blockDim.x + threadIdx.x;
    if (e >= ETOT) return;
    int dst = (e < NE) ? ei[NE + e] : (e - NE);
    atomicAdd(&cnt[dst], 1);
}

// single-block thread-coarsened scan: 1024 threads x 30 contiguous elems
__global__ __launch_bounds__(1024) void scan_kernel(const int* __restrict__ cnt,
                                                    int* __restrict__ rowoff,
                                                    int* __restrict__ fillp) {
    const int CHUNK = 30;   // 1024*30 = 30720 >= NN
    __shared__ int wsum[16];
    int tid = threadIdx.x;
    int base = tid * CHUNK;
    int pref[CHUNK];
    int local = 0;
    #pragma unroll
    for (int i = 0; i < CHUNK; i++) {
        int idx = base + i;
        int c = (idx < NN) ? cnt[idx] : 0;
        pref[i] = local;           // exclusive prefix within thread
        local += c;
    }
    int lane = tid & 63, wave = tid >> 6;
    // wave-level inclusive scan of thread totals
    int incl = local;
    #pragma unroll
    for (int off2 = 1; off2 < 64; off2 <<= 1) {
        int t = __shfl_up(incl, off2);
        if (lane >= off2) incl += t;
    }
    if (lane == 63) wsum[wave] = incl;
    __syncthreads();
    if (wave == 0 && lane < 16) {
        int ws = wsum[lane];
        #pragma unroll
        for (int off2 = 1; off2 < 16; off2 <<= 1) {
            int t = __shfl_up(ws, off2);
            if (lane >= off2) ws += t;
        }
        wsum[lane] = ws;
    }
    __syncthreads();
    int waveoff = (wave > 0) ? wsum[wave - 1] : 0;
    int texcl = waveoff + incl - local;    // exclusive prefix of this thread's chunk
    #pragma unroll
    for (int i = 0; i < CHUNK; i++) {
        int idx = base + i;
        if (idx < NN) {
            int e = texcl + pref[i];
            rowoff[idx] = e;
            fillp[idx]  = e;
        }
    }
    if (tid == 1023) rowoff[NN] = texcl + local;   // == ETOT
}

__global__ void fill_kernel(const int* __restrict__ ei, int* __restrict__ fillp,
                            int* __restrict__ csr) {
    int e = blockIdx.x * blockDim.x + threadIdx.x;
    if (e >= ETOT) return;
    int src, dst;
    if (e < NE) { src = ei[e]; dst = ei[NE + e]; }
    else        { src = e - NE; dst = e - NE; }
    int slot = atomicAdd(&fillp[dst], 1);
    csr[slot] = src;
}

__global__ void ranges_kernel(const int* __restrict__ batch, int* __restrict__ gs,
                              int* __restrict__ ge) {
    int n = blockIdx.x * blockDim.x + threadIdx.x;
    if (n >= NN) return;
    int b = batch[n];
    if (n == 0 || batch[n - 1] != b) gs[b] = n;
    if (n == NN - 1 || batch[n + 1] != b) ge[b] = n + 1;
}

// ---------------- MFMA GEMM: C[MxN] = A[MxK] * BT[NxK]^T, split-bf16 ----------------
// MODE 0: bf16 output, stride PS.  MODE 1: fp32 Q[.,60] + es[.,6] + ed[.,6].

#define LDA 40

template <int MODE>
__global__ __launch_bounds__(256) void gemm_mfma_kernel(
    const unsigned short* __restrict__ Ahi, const unsigned short* __restrict__ Alo,
    const unsigned short* __restrict__ Bhi, const unsigned short* __restrict__ Blo,
    unsigned short* __restrict__ Cbf, float* __restrict__ Cq,
    float* __restrict__ es, float* __restrict__ ed,
    int M, int K, int N, int PS) {
    __shared__ unsigned short sAh[128 * LDA], sAl[128 * LDA];
    __shared__ unsigned short sBh[128 * LDA], sBl[128 * LDA];
    int tid = threadIdx.x;
    int lane = tid & 63, wave = tid >> 6;
    int wr = (wave >> 1) * 64, wc = (wave & 1) * 64;
    int quad = lane >> 4, mr = lane & 15;
    int row0 = blockIdx.y * 128, col0 = blockIdx.x * 128;

    floatx4 zero = {0.f, 0.f, 0.f, 0.f};
    floatx4 acc[4][4];
    #pragma unroll
    for (int i = 0; i < 4; i++)
        #pragma unroll
        for (int j = 0; j < 4; j++) acc[i][j] = zero;

    for (int k0 = 0; k0 < K; k0 += 32) {
        #pragma unroll
        for (int ch = 0; ch < 2; ch++) {
            int linear = (ch * 256 + tid) * 8;   // 128*32 = 4096 elements
            int r = linear >> 5, c = linear & 31;
            uint4 vh, vl;
            int gr = row0 + r;
            if (gr < M) {
                vh = *(const uint4*)(Ahi + (size_t)gr * K + k0 + c);
                vl = *(const uint4*)(Alo + (size_t)gr * K + k0 + c);
            } else { vh = uint4{0, 0, 0, 0}; vl = uint4{0, 0, 0, 0}; }
            *(uint4*)&sAh[r * LDA + c] = vh;
            *(uint4*)&sAl[r * LDA + c] = vl;
            int gn = col0 + r;
            if (gn < N) {
                vh = *(const uint4*)(Bhi + (size_t)gn * K + k0 + c);
                vl = *(const uint4*)(Blo + (size_t)gn * K + k0 + c);
            } else { vh = uint4{0, 0, 0, 0}; vl = uint4{0, 0, 0, 0}; }
            *(uint4*)&sBh[r * LDA + c] = vh;
            *(uint4*)&sBl[r * LDA + c] = vl;
        }
        __syncthreads();

        short8 ah[4], al[4], bh[4], bl[4];
        #pragma unroll
        for (int i = 0; i < 4; i++) {
            int ar = wr + i * 16 + mr;
            ah[i] = *(const short8*)&sAh[ar * LDA + quad * 8];
            al[i] = *(const short8*)&sAl[ar * LDA + quad * 8];
            int br = wc + i * 16 + mr;
            bh[i] = *(const short8*)&sBh[br * LDA + quad * 8];
            bl[i] = *(const short8*)&sBl[br * LDA + quad * 8];
        }
        #pragma unroll
        for (int i = 0; i < 4; i++)
            #pragma unroll
            for (int j = 0; j < 4; j++) {
                acc[i][j] = __builtin_amdgcn_mfma_f32_16x16x32_bf16(ah[i], bh[j], acc[i][j], 0, 0, 0);
                acc[i][j] = __builtin_amdgcn_mfma_f32_16x16x32_bf16(ah[i], bl[j], acc[i][j], 0, 0, 0);
                acc[i][j] = __builtin_amdgcn_mfma_f32_16x16x32_bf16(al[i], bh[j], acc[i][j], 0, 0, 0);
            }
        __syncthreads();
    }

    #pragma unroll
    for (int i = 0; i < 4; i++) {
        #pragma unroll
        for (int j = 0; j < 4; j++) {
            int gc = col0 + wc + j * 16 + mr;
            if (gc >= N) continue;
            int gr0 = row0 + wr + i * 16 + quad * 4;
            #pragma unroll
            for (int r = 0; r < 4; r++) {
                int gr = gr0 + r;
                if (gr >= M) continue;
                float v = acc[i][j][r];
                if (MODE == 0) {
                    Cbf[(size_t)gr * PS + gc] = f2bf(v);
                } else {
                    if (gc < NQ)            Cq[(size_t)gr * NQ + gc] = v;
                    else if (gc < NQ + H3)  es[(size_t)gr * H3 + (gc - NQ)] = v;
                    else                    ed[(size_t)gr * H3 + (gc - NQ - H3)] = v;
                }
            }
        }
    }
}

// ---------------- attention logits (bf16 P), conv1/2 only ----------------

template <int H, int D, int PS>
__global__ void logits_kernel(const unsigned short* __restrict__ P, const float* __restrict__ as_,
                              const float* __restrict__ ad_, float* __restrict__ es,
                              float* __restrict__ ed) {
    int idx = blockIdx.x * blockDim.x + threadIdx.x;
    if (idx >= NN * H) return;
    int node = idx / H, h = idx % H;
    const unsigned short* row = P + (size_t)node * PS + h * D;
    float s1 = 0.f, s2 = 0.f;
    #pragma unroll 4
    for (int d = 0; d < D; d++) {
        float v = bf2f(row[d]);
        s1 += v * as_[h * D + d];
        s2 += v * ad_[h * D + d];
    }
    es[idx] = s1;
    ed[idx] = s2;
}

// ---------------- edge softmax (per dst,head) ----------------

template <int H>
__global__ void edge_softmax_kernel(const float* __restrict__ es, const float* __restrict__ ed,
                                    const int* __restrict__ rowoff, const int* __restrict__ csr,
                                    float* __restrict__ exw, float* __restrict__ invs) {
    int idx = blockIdx.x * blockDim.x + threadIdx.x;
    if (idx >= NN * H) return;
    int node = idx / H, h = idx % H;
    int s0 = rowoff[node], s1 = rowoff[node + 1];
    float edv = ed[idx];
    float mx = -3.4e38f;
    for (int s = s0; s < s1; s++) {
        int src = csr[s];
        float v = es[src * H + h] + edv;
        v = v > 0.f ? v : 0.2f * v;
        mx = fmaxf(mx, v);
    }
    float sum = 0.f;
    for (int s = s0; s < s1; s++) {
        int src = csr[s];
        float v = es[src * H + h] + edv;
        v = v > 0.f ? v : 0.2f * v;
        float ex = expf(v - mx);
        exw[s * H + h] = ex;
        sum += ex;
    }
    invs[idx] = 1.f / (sum + 1e-16f);
}

// ---------------- conv1/2 aggregation: one wave per dst, bf16 gather ----------------

__global__ __launch_bounds__(256) void aggregate12_kernel(
    const unsigned short* __restrict__ P, const float* __restrict__ exw,
    const float* __restrict__ invs, const int* __restrict__ rowoff,
    const int* __restrict__ csr, const float* __restrict__ bias,
    unsigned short* __restrict__ outHi, unsigned short* __restrict__ outLo) {
    int wave = threadIdx.x >> 6, lane = threadIdx.x & 63;
    int dst = blockIdx.x * 4 + wave;           // grid exact: NN/4 blocks
    int head = lane >> 4;                      // 64 feat / head
    float inv = invs[dst * 4 + head];
    float acc0 = 0.f, acc1 = 0.f, acc2 = 0.f, acc3 = 0.f;
    int s0 = rowoff[dst], s1 = rowoff[dst + 1];
    for (int s = s0; s < s1; s++) {
        int src = csr[s];
        ushort4 v = *(const ushort4*)(P + (size_t)src * D1 + lane * 4);
        float w = exw[s * 4 + head] * inv;
        acc0 += w * bf2f(v.x);
        acc1 += w * bf2f(v.y);
        acc2 += w * bf2f(v.z);
        acc3 += w * bf2f(v.w);
    }
    int f0 = lane * 4;
    float a[4] = {acc0, acc1, acc2, acc3};
    ushort4 hi4, lo4;
    unsigned short hh, ll;
    #pragma unroll
    for (int e = 0; e < 4; e++) {
        float v = a[e] + bias[f0 + e];
        v = v > 0.f ? v : expm1f(v);
        split_bf16(v, hh, ll);
        if (e == 0) { hi4.x = hh; lo4.x = ll; }
        else if (e == 1) { hi4.y = hh; lo4.y = ll; }
        else if (e == 2) { hi4.z = hh; lo4.z = ll; }
        else { hi4.w = hh; lo4.w = ll; }
    }
    *(ushort4*)(outHi + (size_t)dst * D1 + f0) = hi4;
    *(ushort4*)(outLo + (size_t)dst * D1 + f0) = lo4;
}

// ---------------- conv3: gather pre-projected Q rows, fused pool+classify accum ----------------

__global__ __launch_bounds__(256) void aggregate3q_kernel(
    const float* __restrict__ Q, const float* __restrict__ exw,
    const float* __restrict__ invs, const int* __restrict__ rowoff,
    const int* __restrict__ csr, const int* __restrict__ batch,
    float* __restrict__ G) {
    int wave = threadIdx.x >> 6, lane = threadIdx.x & 63;
    int dst = blockIdx.x * 4 + wave;           // grid exact: NN/4 blocks
    bool act = lane < NQ;
    int h = lane / NCLS;                       // valid for act
    float inv = act ? invs[dst * H3 + h] : 0.f;
    float acc = 0.f;
    int s0 = rowoff[dst], s1 = rowoff[dst + 1];
    for (int s = s0; s < s1; s++) {
        int src = csr[s];
        float w = act ? exw[s * H3 + h] * inv : 0.f;
        acc += w * Q[(size_t)src * NQ + (act ? lane : 0)];
    }
    // head-sum: lanes c, c+10, ..., c+50
    float tot = acc;
    #pragma unroll
    for (int h2 = 1; h2 < H3; h2++) tot += __shfl(acc, lane + h2 * NCLS);
    if (lane < NCLS) atomicAdd(&G[batch[dst] * NCLS + lane], tot);
}

// ---------------- final: per-graph mean + folded b3 bias + bp ----------------

__global__ __launch_bounds__(64) void final_kernel(
    const float* __restrict__ G, const int* __restrict__ gs, const int* __restrict__ ge,
    const float* __restrict__ b3, const float* __restrict__ wp,
    const float* __restrict__ bp, float* __restrict__ out) {
    int b = blockIdx.x, tid = threadIdx.x;
    if (tid >= NCLS) return;
    int cntn = ge[b] - gs[b];
    float o = bp[tid];
    if (cntn > 0) {
        float bt = 0.f;
        for (int k = 0; k < O3; k++) {
            float bs = 0.f;
            #pragma unroll
            for (int h = 0; h < H3; h++) bs += b3[h * O3 + k];
            bt += bs * wp[k * NCLS + tid];
        }
        o += G[b * NCLS + tid] / (6.f * (float)cntn) + bt * (1.f / 6.f);
    }
    out[b * NCLS + tid] = o;
}

// ---------------- launch ----------------

extern "C" void kernel_launch(void* const* d_in, const int* in_sizes, int n_in,
                              void* d_out, int out_size, void* d_ws, size_t ws_size,
                              hipStream_t stream) {
    const int* x     = (const int*)d_in[0];
    const int* dep   = (const int*)d_in[1];
    const int* ei    = (const int*)d_in[2];
    const int* batch = (const int*)d_in[3];
    const float* nemb = (const float*)d_in[4];
    const float* demb = (const float*)d_in[5];
    const float* w1  = (const float*)d_in[6];
    const float* as1 = (const float*)d_in[7];
    const float* ad1 = (const float*)d_in[8];
    const float* b1  = (const float*)d_in[9];
    const float* w2  = (const float*)d_in[10];
    const float* as2 = (const float*)d_in[11];
    const float* ad2 = (const float*)d_in[12];
    const float* b2  = (const float*)d_in[13];
    const float* w3  = (const float*)d_in[14];
    const float* as3 = (const float*)d_in[15];
    const float* ad3 = (const float*)d_in[16];
    const float* b3  = (const float*)d_in[17];
    const float* wp  = (const float*)d_in[18];
    const float* bp  = (const float*)d_in[19];
    float* out = (float*)d_out;

    char* ws = (char*)d_ws;
    size_t off = 0;
    auto alloc = [&](size_t bytes) -> void* {
        void* p = ws + off;
        off += (bytes + 255) & ~(size_t)255;
        return p;
    };
    unsigned short* Hhi = (unsigned short*)alloc((size_t)NN * D1 * 2);
    unsigned short* Hlo = (unsigned short*)alloc((size_t)NN * D1 * 2);
    unsigned short* Whi = (unsigned short*)alloc((size_t)D1 * D1 * 2);
    unsigned short* Wlo = (unsigned short*)alloc((size_t)D1 * D1 * 2);
    unsigned short* Pb  = (unsigned short*)alloc((size_t)NN * D1 * 2);      // bf16 P (conv1/2)
    float* Q    = (float*)alloc(((size_t)NN * NQ + 64) * 4);                // conv3 pre-projected
    float* G    = (float*)alloc((size_t)NB * NCLS * 4);
    float* es   = (float*)alloc((size_t)NN * 6 * 4);
    float* ed   = (float*)alloc((size_t)NN * 6 * 4);
    float* invs = (float*)alloc((size_t)NN * 6 * 4);
    float* exw  = (float*)alloc((size_t)ETOT * 6 * 4);
    int* cnt    = (int*)alloc((size_t)NN * 4);
    int* rowoff = (int*)alloc((size_t)(NN + 1) * 4);
    int* fillp  = (int*)alloc((size_t)NN * 4);
    int* csr    = (int*)alloc((size_t)ETOT * 4);
    int* gs     = (int*)alloc((size_t)NB * 4);
    int* ge     = (int*)alloc((size_t)NB * 4);

    // --- graph preprocessing ---
    zero_kernel<<<ceil_div(NN, 256), 256, 0, stream>>>(cnt, gs, ge, G);
    h0_kernel<<<ceil_div(NN * EMB, 256), 256, 0, stream>>>(x, dep, nemb, demb, Hhi, Hlo);
    count_kernel<<<ceil_div(ETOT, 256), 256, 0, stream>>>(ei, cnt);
    scan_kernel<<<1, 1024, 0, stream>>>(cnt, rowoff, fillp);
    fill_kernel<<<ceil_div(ETOT, 256), 256, 0, stream>>>(ei, fillp, csr);
    ranges_kernel<<<ceil_div(NN, 256), 256, 0, stream>>>(batch, gs, ge);

    // --- conv1: [NN,64] -> [NN,256], 4 heads x 64 ---
    convB_kernel<<<ceil_div(EMB * D1, 256), 256, 0, stream>>>(w1, Whi, Wlo, EMB, D1);
    gemm_mfma_kernel<0><<<dim3(2, ceil_div(NN, 128)), 256, 0, stream>>>(
        Hhi, Hlo, Whi, Wlo, Pb, nullptr, nullptr, nullptr, NN, EMB, D1, D1);
    logits_kernel<H1, EMB, D1><<<ceil_div(NN * H1, 256), 256, 0, stream>>>(Pb, as1, ad1, es, ed);
    edge_softmax_kernel<H1><<<ceil_div(NN * H1, 256), 256, 0, stream>>>(es, ed, rowoff, csr, exw, invs);
    aggregate12_kernel<<<NN / 4, 256, 0, stream>>>(Pb, exw, invs, rowoff, csr, b1, Hhi, Hlo);

    // --- conv2: [NN,256] -> [NN,256] ---
    convB_kernel<<<ceil_div(D1 * D1, 256), 256, 0, stream>>>(w2, Whi, Wlo, D1, D1);
    gemm_mfma_kernel<0><<<dim3(2, ceil_div(NN, 128)), 256, 0, stream>>>(
        Hhi, Hlo, Whi, Wlo, Pb, nullptr, nullptr, nullptr, NN, D1, D1, D1);
    logits_kernel<H1, EMB, D1><<<ceil_div(NN * H1, 256), 256, 0, stream>>>(Pb, as2, ad2, es, ed);
    edge_softmax_kernel<H1><<<ceil_div(NN * H1, 256), 256, 0, stream>>>(es, ed, rowoff, csr, exw, invs);
    aggregate12_kernel<<<NN / 4, 256, 0, stream>>>(Pb, exw, invs, rowoff, csr, b2, Hhi, Hlo);

    // --- conv3 folded: [NN,256] -> Q[NN,60] + es/ed[NN,6] ---
    prep3_kernel<<<ceil_div(N3 * D1, 256), 256, 0, stream>>>(w3, as3, ad3, wp, Whi, Wlo);
    gemm_mfma_kernel<1><<<dim3(1, ceil_div(NN, 128)), 256, 0, stream>>>(
        Hhi, Hlo, Whi, Wlo, nullptr, Q, es, ed, NN, D1, N3, 0);
    edge_softmax_kernel<H3><<<ceil_div(NN * H3, 256), 256, 0, stream>>>(es, ed, rowoff, csr, exw, invs);
    aggregate3q_kernel<<<NN / 4, 256, 0, stream>>>(Q, exw, invs, rowoff, csr, batch, G);

    // --- final classifier ---
    final_kernel<<<NB, 64, 0, stream>>>(G, gs, ge, b3, wp, bp, out);
}